// Round 1
// baseline (191.284 us; speedup 1.0000x reference)
//
#include <hip/hip_runtime.h>
#include <hip/hip_bf16.h>
#include <cstdint>

// Problem constants (from reference)
#define B_SZ   2
#define L_SEQ  2048
#define HID    4096
#define NH     16
#define NKV    4
#define HD     64
#define NQKV   (NH + 2*NKV)      // 24
#define QKV_N  (NQKV*HD)         // 1536
#define O_N    (NH*HD)           // 1024
#define M_ROWS (B_SZ*L_SEQ)      // 4096
#define EPSV   1e-6f

typedef __bf16  bf16x8_t  __attribute__((ext_vector_type(8)));
typedef float   f32x4_t   __attribute__((ext_vector_type(4)));
typedef unsigned short ushort8_t __attribute__((ext_vector_type(8)));

__device__ __forceinline__ unsigned short f2b(float f) {
    union { float f; uint32_t u; } v; v.f = f;
    uint32_t r = v.u + 0x7FFFu + ((v.u >> 16) & 1u);   // RNE to bf16
    return (unsigned short)(r >> 16);
}

__device__ __forceinline__ void gload_lds16(const void* g, void* l) {
    __builtin_amdgcn_global_load_lds(
        (__attribute__((address_space(1))) void*)(g),
        (__attribute__((address_space(3))) void*)(l),
        16, 0, 0);
}

// ---------------- fp32 -> bf16 elementwise (8 elems/thread) ----------------
__global__ __launch_bounds__(256) void cvt_f32_bf16(const float* __restrict__ in,
                                                    unsigned short* __restrict__ out,
                                                    int n8) {
    int i = blockIdx.x * 256 + threadIdx.x;
    if (i >= n8) return;
    const float4* p = (const float4*)(in + (size_t)i * 8);
    float4 a = p[0], b = p[1];
    ushort8_t o;
    o[0]=f2b(a.x); o[1]=f2b(a.y); o[2]=f2b(a.z); o[3]=f2b(a.w);
    o[4]=f2b(b.x); o[5]=f2b(b.y); o[6]=f2b(b.z); o[7]=f2b(b.w);
    *(ushort8_t*)(out + (size_t)i * 8) = o;
}

// ------------- transpose fp32 (R x C) -> bf16 (C x R) ----------------------
__global__ __launch_bounds__(256) void transpose_f32_bf16(const float* __restrict__ in,
                                                          unsigned short* __restrict__ out,
                                                          int R, int C) {
    __shared__ float t[32][33];
    const int c0 = blockIdx.x * 32;
    const int r0 = blockIdx.y * 32;
    const int tx = threadIdx.x & 31;
    const int ty = threadIdx.x >> 5;   // 0..7
    #pragma unroll
    for (int i = 0; i < 32; i += 8)
        t[ty + i][tx] = in[(size_t)(r0 + ty + i) * C + c0 + tx];
    __syncthreads();
    #pragma unroll
    for (int i = 0; i < 32; i += 8)
        out[(size_t)(c0 + ty + i) * R + r0 + tx] = f2b(t[tx][ty + i]);
}

// ---------------- bf16 GEMM: C[M,N] = A[M,K] * Bt[N,K]^T  (m97 structure) ---
#define BM 128
#define BN 128
#define BK 32

__global__ __launch_bounds__(256) void gemm_bf16(const unsigned short* __restrict__ A,
                                                 const unsigned short* __restrict__ Bt,
                                                 float* __restrict__ C,
                                                 int M, int N, int K) {
    __shared__ unsigned short As[BM * BK];   // 8 KB
    __shared__ unsigned short Bs[BN * BK];   // 8 KB

    const int tid  = threadIdx.x;
    const int lane = tid & 63;
    const int wave = tid >> 6;           // 0..3, 2x2 wave grid
    const int m0 = blockIdx.y * BM;
    const int n0 = blockIdx.x * BN;
    const int wr = (wave >> 1) * 64;
    const int wc = (wave & 1) * 64;
    const int fr = lane & 15;
    const int fq = lane >> 4;

    // staging: thread t covers row = t/4 (+64 for 2nd call), 8-elem chunk (t%4)*8
    const int srow = tid >> 2;
    const int skc  = (tid & 3) * 8;
    const unsigned short* gA = A  + (size_t)(m0 + srow) * K + skc;
    const unsigned short* gB = Bt + (size_t)(n0 + srow) * K + skc;
    unsigned short* lA = As + tid * 8;   // byte off = tid*16 = wave_base + lane*16
    unsigned short* lB = Bs + tid * 8;

    f32x4_t acc[4][4];
    #pragma unroll
    for (int i = 0; i < 4; i++)
        #pragma unroll
        for (int j = 0; j < 4; j++)
            acc[i][j] = (f32x4_t){0.f, 0.f, 0.f, 0.f};

    for (int kt = 0; kt < K; kt += BK) {
        if (kt) __syncthreads();                 // protect LDS from overwrite
        gload_lds16(gA + kt,                 lA);
        gload_lds16(gA + (size_t)64*K + kt,  lA + 64*BK);
        gload_lds16(gB + kt,                 lB);
        gload_lds16(gB + (size_t)64*K + kt,  lB + 64*BK);
        __syncthreads();                         // drains vmcnt before barrier

        bf16x8_t af[4], bfv[4];
        #pragma unroll
        for (int i = 0; i < 4; i++)
            af[i] = *(const bf16x8_t*)&As[(wr + i*16 + fr) * BK + fq*8];
        #pragma unroll
        for (int j = 0; j < 4; j++)
            bfv[j] = *(const bf16x8_t*)&Bs[(wc + j*16 + fr) * BK + fq*8];
        #pragma unroll
        for (int i = 0; i < 4; i++)
            #pragma unroll
            for (int j = 0; j < 4; j++)
                acc[i][j] = __builtin_amdgcn_mfma_f32_16x16x32_bf16(af[i], bfv[j], acc[i][j], 0, 0, 0);
    }

    // C/D layout (m89-verified): col = lane&15, row = (lane>>4)*4 + reg
    const int crow = m0 + wr + fq * 4;
    const int ccol = n0 + wc + fr;
    #pragma unroll
    for (int i = 0; i < 4; i++)
        #pragma unroll
        for (int j = 0; j < 4; j++)
            #pragma unroll
            for (int rr = 0; rr < 4; rr++)
                C[(size_t)(crow + i*16 + rr) * N + ccol + j*16] = acc[i][j][rr];
}

// --------- fused RMSNorm + RoPE + 16-token block-diagonal attention --------
// 1 wave per (b, block, q-head). lane: r = lane>>2 (row 0..15), qp = lane&3
// (16-elem quarter of HD=64).
__global__ __launch_bounds__(64) void attn_fused(const float* __restrict__ qkv,
                                                 const float* __restrict__ cosb,
                                                 const float* __restrict__ sinb,
                                                 const float* __restrict__ qw,
                                                 const float* __restrict__ kw,
                                                 unsigned short* __restrict__ out) {
    const int h    = blockIdx.x & (NH - 1);
    const int blk  = (blockIdx.x >> 4) & 127;
    const int b    = blockIdx.x >> 11;
    const int pos0 = blk * 16;
    const int kvh  = h >> 2;     // groups = NH/NKV = 4

    const int lane = threadIdx.x;
    const int r    = lane >> 2;
    const int qp   = lane & 3;
    const int d0   = qp * 16;

    __shared__ float qs[16][65];   // +1 pad: conflict-free column walks
    __shared__ float ks[16][65];
    __shared__ float vs[16][65];
    __shared__ float ps[16][17];

    const size_t rowb = ((size_t)(b * L_SEQ + pos0 + r)) * NQKV;
    const float* qptr = qkv + (rowb + h) * HD + d0;
    const float* kptr = qkv + (rowb + NH + kvh) * HD + d0;
    const float* vptr = qkv + (rowb + NH + NKV + kvh) * HD + d0;
    const size_t csrow = ((size_t)(b * L_SEQ + pos0 + r)) * HD + d0;

    float q[16], k[16], v[16], cs[16], sn[16];
    #pragma unroll
    for (int i = 0; i < 16; i += 4) {
        *(float4*)&q[i]  = *(const float4*)&qptr[i];
        *(float4*)&k[i]  = *(const float4*)&kptr[i];
        *(float4*)&v[i]  = *(const float4*)&vptr[i];
        *(float4*)&cs[i] = *(const float4*)&cosb[csrow + i];
        *(float4*)&sn[i] = *(const float4*)&sinb[csrow + i];
    }

    // RMSNorm: reduce sum of squares over the 4 lanes sharing row r
    float sq = 0.f, sk = 0.f;
    #pragma unroll
    for (int i = 0; i < 16; i++) { sq += q[i]*q[i]; sk += k[i]*k[i]; }
    sq += __shfl_xor(sq, 1); sq += __shfl_xor(sq, 2);
    sk += __shfl_xor(sk, 1); sk += __shfl_xor(sk, 2);
    const float rq = rsqrtf(sq * (1.f / HD) + EPSV);
    const float rk = rsqrtf(sk * (1.f / HD) + EPSV);

    // RoPE: rotate_half pairs quarter 0<->2, 1<->3 => exchange with lane^2
    const float sgn = (qp < 2) ? -1.f : 1.f;
    #pragma unroll
    for (int i = 0; i < 16; i++) {
        float qn = q[i] * rq * qw[d0 + i];
        float kn = k[i] * rk * kw[d0 + i];
        float qo = __shfl_xor(qn, 2);
        float ko = __shfl_xor(kn, 2);
        qs[r][d0 + i] = qn * cs[i] + sgn * qo * sn[i];
        ks[r][d0 + i] = kn * cs[i] + sgn * ko * sn[i];
        vs[r][d0 + i] = v[i];
    }
    __syncthreads();

    // scores: lane computes s[r][qp + 4*cc], cc=0..3 (dot over HD=64)
    float sc[4] = {0.f, 0.f, 0.f, 0.f};
    for (int d = 0; d < 64; d++) {
        const float qd = qs[r][d];
        sc[0] += qd * ks[qp     ][d];
        sc[1] += qd * ks[qp +  4][d];
        sc[2] += qd * ks[qp +  8][d];
        sc[3] += qd * ks[qp + 12][d];
    }
    #pragma unroll
    for (int cc = 0; cc < 4; cc++) {
        const int c = qp + cc * 4;
        sc[cc] = (c <= r) ? sc[cc] * 0.125f : -3.0e38f;   // causal-in-block mask
    }
    float mx = fmaxf(fmaxf(sc[0], sc[1]), fmaxf(sc[2], sc[3]));
    mx = fmaxf(mx, __shfl_xor(mx, 1));
    mx = fmaxf(mx, __shfl_xor(mx, 2));
    float e[4], sum = 0.f;
    #pragma unroll
    for (int cc = 0; cc < 4; cc++) { e[cc] = __expf(sc[cc] - mx); sum += e[cc]; }
    sum += __shfl_xor(sum, 1); sum += __shfl_xor(sum, 2);
    const float inv = 1.f / sum;
    #pragma unroll
    for (int cc = 0; cc < 4; cc++) ps[r][qp + cc * 4] = e[cc] * inv;
    __syncthreads();

    // PV: o[r][d0..d0+15] = sum_c p[r][c] * v[c][d]
    float o[16];
    #pragma unroll
    for (int i = 0; i < 16; i++) o[i] = 0.f;
    #pragma unroll
    for (int c = 0; c < 16; c++) {
        const float p = ps[r][c];
        #pragma unroll
        for (int i = 0; i < 16; i++) o[i] += p * vs[c][d0 + i];
    }

    __attribute__((aligned(16))) unsigned short ob[16];
    #pragma unroll
    for (int i = 0; i < 16; i++) ob[i] = f2b(o[i]);
    unsigned short* optr = out + (((size_t)(b * L_SEQ + pos0 + r) * NH + h) * HD) + d0;
    *(uint4*)optr       = *(uint4*)&ob[0];
    *((uint4*)optr + 1) = *(uint4*)&ob[8];
}

// ---------------------------------------------------------------------------
extern "C" void kernel_launch(void* const* d_in, const int* in_sizes, int n_in,
                              void* d_out, int out_size, void* d_ws, size_t ws_size,
                              hipStream_t stream) {
    const float* hid  = (const float*)d_in[0];
    // d_in[1] = attention_mask: structural (block-causal), not read
    const float* cosb = (const float*)d_in[2];
    const float* sinb = (const float*)d_in[3];
    const float* Wqkv = (const float*)d_in[4];
    const float* Wo   = (const float*)d_in[5];
    const float* qw   = (const float*)d_in[6];
    const float* kw   = (const float*)d_in[7];
    float* outp = (float*)d_out;

    char* ws = (char*)d_ws;
    unsigned short* Hb    = (unsigned short*)ws; ws += (size_t)M_ROWS * HID * 2;    // 33.5 MB
    unsigned short* WqkvT = (unsigned short*)ws; ws += (size_t)QKV_N * HID * 2;     // 12.6 MB
    unsigned short* WoT   = (unsigned short*)ws; ws += (size_t)HID * O_N * 2;       //  8.4 MB
    float*          qkvf  = (float*)ws;          ws += (size_t)M_ROWS * QKV_N * 4;  // 25.2 MB
    unsigned short* attnb = (unsigned short*)ws;                                    //  8.4 MB

    // 1) hidden fp32 -> bf16
    {
        int n8 = (M_ROWS * HID) / 8;                       // 2097152
        cvt_f32_bf16<<<(n8 + 255) / 256, 256, 0, stream>>>(hid, Hb, n8);
    }
    // 2) weight transposes (B^T layout for MFMA K-contiguous fragments)
    transpose_f32_bf16<<<dim3(QKV_N / 32, HID / 32), 256, 0, stream>>>(Wqkv, WqkvT, HID, QKV_N);
    transpose_f32_bf16<<<dim3(HID / 32, O_N / 32),  256, 0, stream>>>(Wo,   WoT,   O_N, HID);
    // 3) qkv = H @ Wqkv   (4096 x 1536 x 4096)
    gemm_bf16<<<dim3(QKV_N / BN, M_ROWS / BM), 256, 0, stream>>>(Hb, WqkvT, qkvf, M_ROWS, QKV_N, HID);
    // 4) fused rmsnorm + rope + block-diag attention
    attn_fused<<<dim3(B_SZ * (L_SEQ / 16) * NH), 64, 0, stream>>>(qkvf, cosb, sinb, qw, kw, attnb);
    // 5) out = attn @ Wo  (4096 x 4096 x 1024)
    gemm_bf16<<<dim3(HID / BN, M_ROWS / BM), 256, 0, stream>>>(attnb, WoT, outp, M_ROWS, HID, O_N);
}

// Round 2
// 184.225 us; speedup vs baseline: 1.0383x; 1.0383x over previous
//
#include <hip/hip_runtime.h>
#include <hip/hip_bf16.h>
#include <cstdint>

// Problem constants (from reference)
#define B_SZ   2
#define L_SEQ  2048
#define HID    4096
#define NH     16
#define NKV    4
#define HD     64
#define NQKV   (NH + 2*NKV)      // 24
#define QKV_N  (NQKV*HD)         // 1536
#define O_N    (NH*HD)           // 1024
#define M_ROWS (B_SZ*L_SEQ)      // 4096
#define EPSV   1e-6f

typedef __bf16  bf16x8_t  __attribute__((ext_vector_type(8)));
typedef float   f32x4_t   __attribute__((ext_vector_type(4)));
typedef unsigned short ushort8_t __attribute__((ext_vector_type(8)));

__device__ __forceinline__ unsigned short f2b(float f) {
    union { float f; uint32_t u; } v; v.f = f;
    uint32_t r = v.u + 0x7FFFu + ((v.u >> 16) & 1u);   // RNE to bf16
    return (unsigned short)(r >> 16);
}

__device__ __forceinline__ void gload_lds16(const void* g, void* l) {
    __builtin_amdgcn_global_load_lds(
        (__attribute__((address_space(1))) void*)(g),
        (__attribute__((address_space(3))) void*)(l),
        16, 0, 0);
}

// compiler-fenced raw barrier (prevents LDS-op motion across it; zero insts)
#define BARF() do { asm volatile("" ::: "memory"); \
                    __builtin_amdgcn_s_barrier();  \
                    asm volatile("" ::: "memory"); } while (0)
#define LGKM0() do { asm volatile("s_waitcnt lgkmcnt(0)" ::: "memory"); \
                     __builtin_amdgcn_sched_barrier(0); } while (0)
#define VM0()   asm volatile("s_waitcnt vmcnt(0)" ::: "memory")

// ---------------- fp32 -> bf16 elementwise (8 elems/thread) ----------------
__global__ __launch_bounds__(256) void cvt_f32_bf16(const float* __restrict__ in,
                                                    unsigned short* __restrict__ out,
                                                    int n8) {
    int i = blockIdx.x * 256 + threadIdx.x;
    if (i >= n8) return;
    const float4* p = (const float4*)(in + (size_t)i * 8);
    float4 a = p[0], b = p[1];
    ushort8_t o;
    o[0]=f2b(a.x); o[1]=f2b(a.y); o[2]=f2b(a.z); o[3]=f2b(a.w);
    o[4]=f2b(b.x); o[5]=f2b(b.y); o[6]=f2b(b.z); o[7]=f2b(b.w);
    *(ushort8_t*)(out + (size_t)i * 8) = o;
}

// ------------- transpose fp32 (R x C) -> bf16 (C x R) ----------------------
__global__ __launch_bounds__(256) void transpose_f32_bf16(const float* __restrict__ in,
                                                          unsigned short* __restrict__ out,
                                                          int R, int C) {
    __shared__ float t[32][33];
    const int c0 = blockIdx.x * 32;
    const int r0 = blockIdx.y * 32;
    const int tx = threadIdx.x & 31;
    const int ty = threadIdx.x >> 5;   // 0..7
    #pragma unroll
    for (int i = 0; i < 32; i += 8)
        t[ty + i][tx] = in[(size_t)(r0 + ty + i) * C + c0 + tx];
    __syncthreads();
    #pragma unroll
    for (int i = 0; i < 32; i += 8)
        out[(size_t)(c0 + ty + i) * R + r0 + tx] = f2b(t[tx][ty + i]);
}

// ------- bf16 GEMM 128x128 (m97 structure + explicit dbuf prefetch) --------
#define BM 128
#define BN 128
#define BK 32

__global__ __launch_bounds__(256) void gemm_bf16(const unsigned short* __restrict__ A,
                                                 const unsigned short* __restrict__ Bt,
                                                 float* __restrict__ C,
                                                 int M, int N, int K) {
    __shared__ unsigned short As[2][BM * BK];   // 2 x 8 KB
    __shared__ unsigned short Bs[2][BN * BK];   // 2 x 8 KB

    const int tid  = threadIdx.x;
    const int lane = tid & 63;
    const int wave = tid >> 6;           // 0..3, 2x2 wave grid
    const int m0 = blockIdx.y * BM;
    const int n0 = blockIdx.x * BN;
    const int wr = (wave >> 1) * 64;
    const int wc = (wave & 1) * 64;
    const int fr = lane & 15;
    const int fq = lane >> 4;

    const int srow = tid >> 2;
    const int skc  = (tid & 3) * 8;
    const unsigned short* gA = A  + (size_t)(m0 + srow) * K + skc;
    const unsigned short* gB = Bt + (size_t)(n0 + srow) * K + skc;

    f32x4_t acc[4][4];
    #pragma unroll
    for (int i = 0; i < 4; i++)
        #pragma unroll
        for (int j = 0; j < 4; j++)
            acc[i][j] = (f32x4_t){0.f, 0.f, 0.f, 0.f};

    // prologue: stage tile 0 into buf 0
    gload_lds16(gA,                &As[0][tid*8]);
    gload_lds16(gA + (size_t)64*K, &As[0][64*BK + tid*8]);
    gload_lds16(gB,                &Bs[0][tid*8]);
    gload_lds16(gB + (size_t)64*K, &Bs[0][64*BK + tid*8]);
    __syncthreads();

    for (int kt = 0; kt < K; kt += BK) {
        const int cur = (kt >> 5) & 1;
        const int nxt = cur ^ 1;
        if (kt + BK < K) {   // issue next-tile staging BEFORE compute (overlap)
            gload_lds16(gA + kt + BK,                &As[nxt][tid*8]);
            gload_lds16(gA + (size_t)64*K + kt + BK, &As[nxt][64*BK + tid*8]);
            gload_lds16(gB + kt + BK,                &Bs[nxt][tid*8]);
            gload_lds16(gB + (size_t)64*K + kt + BK, &Bs[nxt][64*BK + tid*8]);
        }

        bf16x8_t af[4], bfv[4];
        #pragma unroll
        for (int i = 0; i < 4; i++)
            af[i] = *(const bf16x8_t*)&As[cur][(wr + i*16 + fr) * BK + fq*8];
        #pragma unroll
        for (int j = 0; j < 4; j++)
            bfv[j] = *(const bf16x8_t*)&Bs[cur][(wc + j*16 + fr) * BK + fq*8];
        #pragma unroll
        for (int i = 0; i < 4; i++)
            #pragma unroll
            for (int j = 0; j < 4; j++)
                acc[i][j] = __builtin_amdgcn_mfma_f32_16x16x32_bf16(af[i], bfv[j], acc[i][j], 0, 0, 0);

        __syncthreads();   // drains this iter's staging; one barrier per tile
    }

    const int crow = m0 + wr + fq * 4;
    const int ccol = n0 + wc + fr;
    #pragma unroll
    for (int i = 0; i < 4; i++)
        #pragma unroll
        for (int j = 0; j < 4; j++)
            #pragma unroll
            for (int rr = 0; rr < 4; rr++)
                C[(size_t)(crow + i*16 + rr) * N + ccol + j*16] = acc[i][j][rr];
}

// ------- bf16 GEMM 256x256, 8-wave, BK=64, 4-phase/K-tile, T2 swizzle ------
// LDS: 2 buffers x (A 256x64 | B 256x64) bf16 = 128 KiB. 1 block/CU.
// Swizzle: 16B chunk c within a 128B row r stored at c ^ (r&7) (involution;
// applied on BOTH the pre-swizzled global source and the ds_read address).
__global__ __launch_bounds__(512, 2) void gemm256_bf16(const unsigned short* __restrict__ A,
                                                       const unsigned short* __restrict__ Bt,
                                                       float* __restrict__ C,
                                                       int M, int N, int K) {
    __shared__ unsigned short smem[65536];   // 128 KiB

    const int tid  = threadIdx.x;
    const int lane = tid & 63;
    const int wave = tid >> 6;         // 0..7
    const int wr   = wave >> 2;        // 0..1  (M half, 128 rows)
    const int wc   = wave & 3;         // 0..3  (N quarter, 64 cols)
    const int fr   = lane & 15;
    const int fq   = lane >> 4;

    // XCD-aware bijective swizzle (gridDim.x % 8 == 0)
    const int nbx = N >> 8;
    int bid = blockIdx.x;
    const int cpx = gridDim.x >> 3;
    bid = (bid & 7) * cpx + (bid >> 3);
    const int bx = bid % nbx, by = bid / nbx;
    const int m0 = by << 8, n0 = bx << 8;

    // staging constants: round q covers rows q*64 + (tid>>3), phys chunk tid&7
    const int srow = tid >> 3;
    const int scs  = ((tid & 7) ^ (srow & 7)) << 3;   // pre-swizzled src k-off
    const unsigned short* gA = A  + (size_t)(m0 + srow) * K + scs;
    const unsigned short* gB = Bt + (size_t)(n0 + srow) * K + scs;

    // frag-read swizzled chunk offsets (row&7 == fr&7 for all frag rows)
    const int cx0 = ((fq)     ^ (fr & 7)) << 3;   // kk=0
    const int cx1 = ((4 | fq) ^ (fr & 7)) << 3;   // kk=1

    f32x4_t acc[8][4];
    #pragma unroll
    for (int m = 0; m < 8; m++)
        #pragma unroll
        for (int n = 0; n < 4; n++)
            acc[m][n] = (f32x4_t){0.f, 0.f, 0.f, 0.f};

    bf16x8_t aF[4][2];   // current M-half fragments
    bf16x8_t bF[4][2];   // all 4 N fragments (live across the tile)

#define STAGE_A256(KT, PB) { _Pragma("unroll") for (int q = 0; q < 4; ++q) \
    gload_lds16(gA + (size_t)(q*64)*K + (KT), &smem[(PB) + q*4096 + tid*8]); }
#define STAGE_B256(KT, PB) { _Pragma("unroll") for (int q = 0; q < 4; ++q) \
    gload_lds16(gB + (size_t)(q*64)*K + (KT), &smem[(PB) + 16384 + q*4096 + tid*8]); }
#define READ_A256(SB, MH) { _Pragma("unroll") for (int mm = 0; mm < 4; ++mm) { \
    const int ro = (SB) + (wr*128 + (MH)*64 + mm*16 + fr)*64; \
    aF[mm][0] = *(const bf16x8_t*)&smem[ro + cx0]; \
    aF[mm][1] = *(const bf16x8_t*)&smem[ro + cx1]; } }
#define READ_B256(SB, NLO) { _Pragma("unroll") for (int nn = 0; nn < 2; ++nn) { \
    const int ro = (SB) + 16384 + (wc*64 + ((NLO)+nn)*16 + fr)*64; \
    bF[(NLO)+nn][0] = *(const bf16x8_t*)&smem[ro + cx0]; \
    bF[(NLO)+nn][1] = *(const bf16x8_t*)&smem[ro + cx1]; } }
#define MFMA16(MH, NLO) { __builtin_amdgcn_s_setprio(1); \
    _Pragma("unroll") for (int mm = 0; mm < 4; ++mm) \
    _Pragma("unroll") for (int nn = 0; nn < 2; ++nn) \
    _Pragma("unroll") for (int kk = 0; kk < 2; ++kk) \
        acc[(MH)*4+mm][(NLO)+nn] = __builtin_amdgcn_mfma_f32_16x16x32_bf16( \
            aF[mm][kk], bF[(NLO)+nn][kk], acc[(MH)*4+mm][(NLO)+nn], 0, 0, 0); \
    __builtin_amdgcn_s_setprio(0); }

    const int NT = K >> 6;
    // prologue: stage tile 0 into buf 0
    STAGE_A256(0, 0);
    STAGE_B256(0, 0);
    __syncthreads();

    for (int t = 0; t < NT; ++t) {
        const int sb  = (t & 1) << 15;          // current buffer (shorts)
        const int pb  = sb ^ 32768;             // prefetch buffer
        const int ktn = (t + 1) << 6;
        const bool pf = (t + 1 < NT);

        // phase 1: read A-half0 + B n0,n1 ; issue A(t+1) staging
        READ_A256(sb, 0); READ_B256(sb, 0);
        if (pf) STAGE_A256(ktn, pb);
        BARF(); LGKM0(); MFMA16(0, 0); BARF();

        // phase 2: read B n2,n3 ; issue B(t+1) staging
        READ_B256(sb, 2);
        if (pf) STAGE_B256(ktn, pb);
        BARF(); LGKM0(); MFMA16(0, 2); BARF();

        // phase 3: read A-half1
        READ_A256(sb, 1);
        BARF(); LGKM0(); MFMA16(1, 2); BARF();

        // phase 4: pure MFMA; drain prefetch once per tile
        MFMA16(1, 0);
        VM0(); BARF();
    }

    // epilogue: C/D layout col=lane&15, row=(lane>>4)*4+reg
    const int crow = m0 + wr * 128 + fq * 4;
    const int ccol = n0 + wc * 64 + fr;
    #pragma unroll
    for (int m = 0; m < 8; m++)
        #pragma unroll
        for (int n = 0; n < 4; n++)
            #pragma unroll
            for (int rr = 0; rr < 4; rr++)
                C[(size_t)(crow + m*16 + rr) * N + ccol + n*16] = acc[m][n][rr];
#undef STAGE_A256
#undef STAGE_B256
#undef READ_A256
#undef READ_B256
#undef MFMA16
}

// --------- fused RMSNorm + RoPE + 16-token block-diagonal attention --------
__global__ __launch_bounds__(64) void attn_fused(const float* __restrict__ qkv,
                                                 const float* __restrict__ cosb,
                                                 const float* __restrict__ sinb,
                                                 const float* __restrict__ qw,
                                                 const float* __restrict__ kw,
                                                 unsigned short* __restrict__ out) {
    const int h    = blockIdx.x & (NH - 1);
    const int blk  = (blockIdx.x >> 4) & 127;
    const int b    = blockIdx.x >> 11;
    const int pos0 = blk * 16;
    const int kvh  = h >> 2;

    const int lane = threadIdx.x;
    const int r    = lane >> 2;
    const int qp   = lane & 3;
    const int d0   = qp * 16;

    __shared__ float qs[16][65];
    __shared__ float ks[16][65];
    __shared__ float vs[16][65];
    __shared__ float ps[16][17];

    const size_t rowb = ((size_t)(b * L_SEQ + pos0 + r)) * NQKV;
    const float* qptr = qkv + (rowb + h) * HD + d0;
    const float* kptr = qkv + (rowb + NH + kvh) * HD + d0;
    const float* vptr = qkv + (rowb + NH + NKV + kvh) * HD + d0;
    const size_t csrow = ((size_t)(b * L_SEQ + pos0 + r)) * HD + d0;

    float q[16], k[16], v[16], cs[16], sn[16];
    #pragma unroll
    for (int i = 0; i < 16; i += 4) {
        *(float4*)&q[i]  = *(const float4*)&qptr[i];
        *(float4*)&k[i]  = *(const float4*)&kptr[i];
        *(float4*)&v[i]  = *(const float4*)&vptr[i];
        *(float4*)&cs[i] = *(const float4*)&cosb[csrow + i];
        *(float4*)&sn[i] = *(const float4*)&sinb[csrow + i];
    }

    float sq = 0.f, sk = 0.f;
    #pragma unroll
    for (int i = 0; i < 16; i++) { sq += q[i]*q[i]; sk += k[i]*k[i]; }
    sq += __shfl_xor(sq, 1); sq += __shfl_xor(sq, 2);
    sk += __shfl_xor(sk, 1); sk += __shfl_xor(sk, 2);
    const float rq = rsqrtf(sq * (1.f / HD) + EPSV);
    const float rk = rsqrtf(sk * (1.f / HD) + EPSV);

    const float sgn = (qp < 2) ? -1.f : 1.f;
    #pragma unroll
    for (int i = 0; i < 16; i++) {
        float qn = q[i] * rq * qw[d0 + i];
        float kn = k[i] * rk * kw[d0 + i];
        float qo = __shfl_xor(qn, 2);
        float ko = __shfl_xor(kn, 2);
        qs[r][d0 + i] = qn * cs[i] + sgn * qo * sn[i];
        ks[r][d0 + i] = kn * cs[i] + sgn * ko * sn[i];
        vs[r][d0 + i] = v[i];
    }
    __syncthreads();

    float sc[4] = {0.f, 0.f, 0.f, 0.f};
    for (int d = 0; d < 64; d++) {
        const float qd = qs[r][d];
        sc[0] += qd * ks[qp     ][d];
        sc[1] += qd * ks[qp +  4][d];
        sc[2] += qd * ks[qp +  8][d];
        sc[3] += qd * ks[qp + 12][d];
    }
    #pragma unroll
    for (int cc = 0; cc < 4; cc++) {
        const int c = qp + cc * 4;
        sc[cc] = (c <= r) ? sc[cc] * 0.125f : -3.0e38f;
    }
    float mx = fmaxf(fmaxf(sc[0], sc[1]), fmaxf(sc[2], sc[3]));
    mx = fmaxf(mx, __shfl_xor(mx, 1));
    mx = fmaxf(mx, __shfl_xor(mx, 2));
    float e[4], sum = 0.f;
    #pragma unroll
    for (int cc = 0; cc < 4; cc++) { e[cc] = __expf(sc[cc] - mx); sum += e[cc]; }
    sum += __shfl_xor(sum, 1); sum += __shfl_xor(sum, 2);
    const float inv = 1.f / sum;
    #pragma unroll
    for (int cc = 0; cc < 4; cc++) ps[r][qp + cc * 4] = e[cc] * inv;
    __syncthreads();

    float o[16];
    #pragma unroll
    for (int i = 0; i < 16; i++) o[i] = 0.f;
    #pragma unroll
    for (int c = 0; c < 16; c++) {
        const float p = ps[r][c];
        #pragma unroll
        for (int i = 0; i < 16; i++) o[i] += p * vs[c][d0 + i];
    }

    __attribute__((aligned(16))) unsigned short ob[16];
    #pragma unroll
    for (int i = 0; i < 16; i++) ob[i] = f2b(o[i]);
    unsigned short* optr = out + (((size_t)(b * L_SEQ + pos0 + r) * NH + h) * HD) + d0;
    *(uint4*)optr       = *(uint4*)&ob[0];
    *((uint4*)optr + 1) = *(uint4*)&ob[8];
}

// ---------------------------------------------------------------------------
extern "C" void kernel_launch(void* const* d_in, const int* in_sizes, int n_in,
                              void* d_out, int out_size, void* d_ws, size_t ws_size,
                              hipStream_t stream) {
    const float* hid  = (const float*)d_in[0];
    const float* cosb = (const float*)d_in[2];
    const float* sinb = (const float*)d_in[3];
    const float* Wqkv = (const float*)d_in[4];
    const float* Wo   = (const float*)d_in[5];
    const float* qw   = (const float*)d_in[6];
    const float* kw   = (const float*)d_in[7];
    float* outp = (float*)d_out;

    char* ws = (char*)d_ws;
    unsigned short* Hb    = (unsigned short*)ws; ws += (size_t)M_ROWS * HID * 2;
    unsigned short* WqkvT = (unsigned short*)ws; ws += (size_t)QKV_N * HID * 2;
    unsigned short* WoT   = (unsigned short*)ws; ws += (size_t)HID * O_N * 2;
    float*          qkvf  = (float*)ws;          ws += (size_t)M_ROWS * QKV_N * 4;
    unsigned short* attnb = (unsigned short*)ws;

    {
        int n8 = (M_ROWS * HID) / 8;
        cvt_f32_bf16<<<(n8 + 255) / 256, 256, 0, stream>>>(hid, Hb, n8);
    }
    transpose_f32_bf16<<<dim3(QKV_N / 32, HID / 32), 256, 0, stream>>>(Wqkv, WqkvT, HID, QKV_N);
    transpose_f32_bf16<<<dim3(HID / 32, O_N / 32),  256, 0, stream>>>(Wo,   WoT,   O_N, HID);
    // qkv = H @ Wqkv   (4096 x 1536 x 4096), 128^2 tiles + dbuf prefetch
    gemm_bf16<<<dim3(QKV_N / BN, M_ROWS / BM), 256, 0, stream>>>(Hb, WqkvT, qkvf, M_ROWS, QKV_N, HID);
    // fused rmsnorm + rope + block-diag attention
    attn_fused<<<dim3(B_SZ * (L_SEQ / 16) * NH), 64, 0, stream>>>(qkvf, cosb, sinb, qw, kw, attnb);
    // out = attn @ Wo  (4096 x 4096 x 1024), 256^2 8-wave 4-phase template
    gemm256_bf16<<<dim3((M_ROWS / 256) * (HID / 256)), 512, 0, stream>>>(attnb, WoT, outp, M_ROWS, HID, O_N);
}

// Round 3
// 161.778 us; speedup vs baseline: 1.1824x; 1.1388x over previous
//
#include <hip/hip_runtime.h>
#include <hip/hip_bf16.h>
#include <cstdint>

// Problem constants (from reference)
#define B_SZ   2
#define L_SEQ  2048
#define HID    4096
#define NH     16
#define NKV    4
#define HD     64
#define NQKV   (NH + 2*NKV)      // 24
#define QKV_N  (NQKV*HD)         // 1536
#define O_N    (NH*HD)           // 1024
#define M_ROWS (B_SZ*L_SEQ)      // 4096
#define EPSV   1e-6f

typedef __bf16  bf16x8_t  __attribute__((ext_vector_type(8)));
typedef float   f32x4_t   __attribute__((ext_vector_type(4)));
typedef unsigned short ushort8_t __attribute__((ext_vector_type(8)));

__device__ __forceinline__ unsigned short f2b(float f) {
    union { float f; uint32_t u; } v; v.f = f;
    uint32_t r = v.u + 0x7FFFu + ((v.u >> 16) & 1u);   // RNE to bf16
    return (unsigned short)(r >> 16);
}

__device__ __forceinline__ void gload_lds16(const void* g, void* l) {
    __builtin_amdgcn_global_load_lds(
        (__attribute__((address_space(1))) void*)(g),
        (__attribute__((address_space(3))) void*)(l),
        16, 0, 0);
}

#define BARF() do { asm volatile("" ::: "memory"); \
                    __builtin_amdgcn_s_barrier();  \
                    asm volatile("" ::: "memory"); } while (0)
#define LGKM0() do { asm volatile("s_waitcnt lgkmcnt(0)" ::: "memory"); \
                     __builtin_amdgcn_sched_barrier(0); } while (0)
#define VMC4()  asm volatile("s_waitcnt vmcnt(4)" ::: "memory")
#define VMC0()  asm volatile("s_waitcnt vmcnt(0)" ::: "memory")

// ---------------- fp32 -> bf16 elementwise (8 elems/thread) ----------------
__global__ __launch_bounds__(256) void cvt_f32_bf16(const float* __restrict__ in,
                                                    unsigned short* __restrict__ out,
                                                    int n8) {
    int i = blockIdx.x * 256 + threadIdx.x;
    if (i >= n8) return;
    const float4* p = (const float4*)(in + (size_t)i * 8);
    float4 a = p[0], b = p[1];
    ushort8_t o;
    o[0]=f2b(a.x); o[1]=f2b(a.y); o[2]=f2b(a.z); o[3]=f2b(a.w);
    o[4]=f2b(b.x); o[5]=f2b(b.y); o[6]=f2b(b.z); o[7]=f2b(b.w);
    *(ushort8_t*)(out + (size_t)i * 8) = o;
}

// ------------- transpose fp32 (R x C) -> bf16 (C x R) ----------------------
__global__ __launch_bounds__(256) void transpose_f32_bf16(const float* __restrict__ in,
                                                          unsigned short* __restrict__ out,
                                                          int R, int C) {
    __shared__ float t[32][33];
    const int c0 = blockIdx.x * 32;
    const int r0 = blockIdx.y * 32;
    const int tx = threadIdx.x & 31;
    const int ty = threadIdx.x >> 5;
    #pragma unroll
    for (int i = 0; i < 32; i += 8)
        t[ty + i][tx] = in[(size_t)(r0 + ty + i) * C + c0 + tx];
    __syncthreads();
    #pragma unroll
    for (int i = 0; i < 32; i += 8)
        out[(size_t)(c0 + ty + i) * R + r0 + tx] = f2b(t[tx][ty + i]);
}

// ===========================================================================
// GEMM 256x256, BK=64, 8 waves (2M x 4N), 4-phase counted-vmcnt schedule.
// LDS 128 KiB: buf s at s*32768 shorts; A [256][64] + B(+16384) [256][64].
// T2 swizzle: 16B chunk c of 128B row r stored at c^(r&7); pre-swizzled
// global source (m173) + swizzled ds_read offsets.
// Staging: A(t+1) halves @p1,p2 (other buffer); B(t+2) halves @p3,p4 (own
// buffer B region, consumed @p1). vmcnt(4) per tile => tile t+1 fully landed.
// ===========================================================================
__global__ __launch_bounds__(512, 2) void gemm256_bf16(const unsigned short* __restrict__ A,
                                                       const unsigned short* __restrict__ Bt,
                                                       float* __restrict__ C,
                                                       int M, int N, int K) {
    __shared__ unsigned short smem[65536];   // 128 KiB

    const int tid  = threadIdx.x;
    const int lane = tid & 63;
    const int wave = tid >> 6;         // 0..7
    const int wr   = wave >> 2;        // 0..1  M-half (128 rows)
    const int wc   = wave & 3;         // 0..3  N-quarter (64 cols)
    const int fr   = lane & 15;
    const int fq   = lane >> 4;

    // XCD-aware bijective swizzle (gridDim.x % 8 == 0)
    const int nbx = N >> 8;
    int bid = blockIdx.x;
    const int cpx = gridDim.x >> 3;
    bid = (bid & 7) * cpx + (bid >> 3);
    const int bx = bid % nbx, by = bid / nbx;
    const int m0 = by << 8, n0 = bx << 8;

    const int srow = tid >> 3;
    const int scs  = ((tid & 7) ^ (srow & 7)) << 3;   // pre-swizzled src k-off
    const unsigned short* gA = A  + (size_t)(m0 + srow) * K + scs;
    const unsigned short* gB = Bt + (size_t)(n0 + srow) * K + scs;

    const int cx0 = ((fq)     ^ (fr & 7)) << 3;
    const int cx1 = ((4 | fq) ^ (fr & 7)) << 3;

    f32x4_t acc[8][4];
    #pragma unroll
    for (int m = 0; m < 8; m++)
        #pragma unroll
        for (int n = 0; n < 4; n++)
            acc[m][n] = (f32x4_t){0.f, 0.f, 0.f, 0.f};

    bf16x8_t aF[2][2];   // current mm-pair fragments
    bf16x8_t bF[4][2];   // all 4 nn fragments (live across the tile)

#define STG_A2(T, H) { _Pragma("unroll") for (int q = 0; q < 2; ++q) \
    gload_lds16(gA + (size_t)((H)*128 + q*64) * K + ((size_t)(T) << 6), \
                &smem[(((T)&1)<<15) + ((H)*128 + q*64)*64 + tid*8]); }
#define STG_B2(T, H) { _Pragma("unroll") for (int q = 0; q < 2; ++q) \
    gload_lds16(gB + (size_t)((H)*128 + q*64) * K + ((size_t)(T) << 6), \
                &smem[(((T)&1)<<15) + 16384 + ((H)*128 + q*64)*64 + tid*8]); }
#define RD_B2(SB) { _Pragma("unroll") for (int nn = 0; nn < 4; ++nn) { \
    const int ro = (SB) + 16384 + (wc*64 + nn*16 + fr)*64; \
    bF[nn][0] = *(const bf16x8_t*)&smem[ro + cx0]; \
    bF[nn][1] = *(const bf16x8_t*)&smem[ro + cx1]; } }
#define RD_A2(SB, P) { _Pragma("unroll") for (int m2 = 0; m2 < 2; ++m2) { \
    const int ro = (SB) + (wr*128 + ((P)*2 + m2)*16 + fr)*64; \
    aF[m2][0] = *(const bf16x8_t*)&smem[ro + cx0]; \
    aF[m2][1] = *(const bf16x8_t*)&smem[ro + cx1]; } }
#define MM2(P) { __builtin_amdgcn_s_setprio(1); \
    _Pragma("unroll") for (int m2 = 0; m2 < 2; ++m2) \
    _Pragma("unroll") for (int nn = 0; nn < 4; ++nn) \
    _Pragma("unroll") for (int kk = 0; kk < 2; ++kk) \
        acc[(P)*2 + m2][nn] = __builtin_amdgcn_mfma_f32_16x16x32_bf16( \
            aF[m2][kk], bF[nn][kk], acc[(P)*2 + m2][nn], 0, 0, 0); \
    __builtin_amdgcn_s_setprio(0); }

    const int NT = K >> 6;
    // prologue: tile0 complete + tile1 B
    STG_A2(0, 0); STG_A2(0, 1); STG_B2(0, 0); STG_B2(0, 1);
    STG_B2(1, 0); STG_B2(1, 1);
    VMC4();                      // tile0 landed (outstanding = tile1 B, 4 loads)
    BARF();

    for (int t = 0; t < NT; ++t) {
        const int sb = (t & 1) << 15;
        // p1: B fully read + A mm0-1; stage HA0(t+1) -> other buffer
        RD_B2(sb); RD_A2(sb, 0);
        if (t + 1 < NT) STG_A2(t + 1, 0);
        BARF(); LGKM0(); MM2(0); BARF();
        // p2: A mm2-3; stage HA1(t+1)
        RD_A2(sb, 1);
        if (t + 1 < NT) STG_A2(t + 1, 1);
        BARF(); LGKM0(); MM2(1); BARF();
        // p3: A mm4-5; stage HB0(t+2) -> own B region (consumed @p1)
        RD_A2(sb, 2);
        if (t + 2 < NT) STG_B2(t + 2, 0);
        BARF(); LGKM0(); MM2(2); BARF();
        // p4: A mm6-7; stage HB1(t+2); counted drain
        RD_A2(sb, 3);
        if (t + 2 < NT) STG_B2(t + 2, 1);
        BARF(); LGKM0(); MM2(3);
        if (t + 2 < NT) { VMC4(); } else { VMC0(); }
        BARF();
    }

    const int crow = m0 + wr * 128 + fq * 4;
    const int ccol = n0 + wc * 64 + fr;
    #pragma unroll
    for (int m = 0; m < 8; m++)
        #pragma unroll
        for (int n = 0; n < 4; n++)
            #pragma unroll
            for (int rr = 0; rr < 4; rr++)
                C[(size_t)(crow + m*16 + rr) * N + ccol + n*16] = acc[m][n][rr];
#undef STG_A2
#undef STG_B2
#undef RD_B2
#undef RD_A2
#undef MM2
}

// ===========================================================================
// GEMM 256x128, BK=64, 8 waves (4M x 2N, per-wave 64x64), 4-phase schedule.
// LDS 96 KiB: buf s at s*24576 shorts; A [256][64] + B(+16384) [128][64].
// Quadrant order: (mm01,nn01) (mm01,nn23) (mm23,nn23) (mm23,nn01).
// Staging: HA1(t+1)@p1, B(t+2)@p3 (B consumed @p2), HA0(t+2)@p4 (A consumed
// @p3). vmcnt(4) per tile => tile t+1 fully landed.
// ===========================================================================
__global__ __launch_bounds__(512, 2) void gemm256x128_bf16(const unsigned short* __restrict__ A,
                                                           const unsigned short* __restrict__ Bt,
                                                           float* __restrict__ C,
                                                           int M, int N, int K) {
    __shared__ unsigned short smem[49152];   // 96 KiB

    const int tid  = threadIdx.x;
    const int lane = tid & 63;
    const int wave = tid >> 6;         // 0..7
    const int wq   = wave >> 1;        // 0..3  M-quarter (64 rows)
    const int wn   = wave & 1;         // 0..1  N-half (64 cols)
    const int fr   = lane & 15;
    const int fq   = lane >> 4;

    const int nbx = N >> 7;            // 128-wide N tiles
    int bid = blockIdx.x;
    const int cpx = gridDim.x >> 3;
    bid = (bid & 7) * cpx + (bid >> 3);
    const int bx = bid % nbx, by = bid / nbx;
    const int m0 = by << 8, n0 = bx << 7;

    const int srow = tid >> 3;
    const int scs  = ((tid & 7) ^ (srow & 7)) << 3;
    const unsigned short* gA = A  + (size_t)(m0 + srow) * K + scs;
    const unsigned short* gB = Bt + (size_t)(n0 + srow) * K + scs;

    const int cx0 = ((fq)     ^ (fr & 7)) << 3;
    const int cx1 = ((4 | fq) ^ (fr & 7)) << 3;

    f32x4_t acc[4][4];
    #pragma unroll
    for (int m = 0; m < 4; m++)
        #pragma unroll
        for (int n = 0; n < 4; n++)
            acc[m][n] = (f32x4_t){0.f, 0.f, 0.f, 0.f};

    bf16x8_t aF[4][2];
    bf16x8_t bF[4][2];

#define STG_A1(T, H) { _Pragma("unroll") for (int q = 0; q < 2; ++q) \
    gload_lds16(gA + (size_t)((H)*128 + q*64) * K + ((size_t)(T) << 6), \
                &smem[((T)&1)*24576 + ((H)*128 + q*64)*64 + tid*8]); }
#define STG_B1(T) { _Pragma("unroll") for (int q = 0; q < 2; ++q) \
    gload_lds16(gB + (size_t)(q*64) * K + ((size_t)(T) << 6), \
                &smem[((T)&1)*24576 + 16384 + q*4096 + tid*8]); }
#define RD_A1(SB, MM) { _Pragma("unroll") for (int m2 = 0; m2 < 2; ++m2) { \
    const int ro = (SB) + (wq*64 + ((MM) + m2)*16 + fr)*64; \
    aF[(MM)+m2][0] = *(const bf16x8_t*)&smem[ro + cx0]; \
    aF[(MM)+m2][1] = *(const bf16x8_t*)&smem[ro + cx1]; } }
#define RD_B1(SB, NN) { _Pragma("unroll") for (int n2 = 0; n2 < 2; ++n2) { \
    const int ro = (SB) + 16384 + (wn*64 + ((NN) + n2)*16 + fr)*64; \
    bF[(NN)+n2][0] = *(const bf16x8_t*)&smem[ro + cx0]; \
    bF[(NN)+n2][1] = *(const bf16x8_t*)&smem[ro + cx1]; } }
#define MM1(MH, NH) { __builtin_amdgcn_s_setprio(1); \
    _Pragma("unroll") for (int m2 = 0; m2 < 2; ++m2) \
    _Pragma("unroll") for (int n2 = 0; n2 < 2; ++n2) \
    _Pragma("unroll") for (int kk = 0; kk < 2; ++kk) \
        acc[(MH)*2 + m2][(NH)*2 + n2] = __builtin_amdgcn_mfma_f32_16x16x32_bf16( \
            aF[(MH)*2 + m2][kk], bF[(NH)*2 + n2][kk], acc[(MH)*2 + m2][(NH)*2 + n2], 0, 0, 0); \
    __builtin_amdgcn_s_setprio(0); }

    const int NT = K >> 6;
    // prologue: tile0 complete + tile1 B + tile1 HA0
    STG_A1(0, 0); STG_A1(0, 1); STG_B1(0);
    STG_B1(1); STG_A1(1, 0);
    VMC4();                      // tile0 landed (outstanding = B(1)+HA0(1))
    BARF();

    for (int t = 0; t < NT; ++t) {
        const int sb = (t & 1) * 24576;
        // p1: aF mm0-1 + bF nn0-1; stage HA1(t+1)
        RD_A1(sb, 0); RD_B1(sb, 0);
        if (t + 1 < NT) STG_A1(t + 1, 1);
        BARF(); LGKM0(); MM1(0, 0); BARF();
        // p2: bF nn2-3
        RD_B1(sb, 2);
        BARF(); LGKM0(); MM1(0, 1); BARF();
        // p3: aF mm2-3; stage B(t+2) (B region consumed @p2)
        RD_A1(sb, 2);
        if (t + 2 < NT) STG_B1(t + 2);
        BARF(); LGKM0(); MM1(1, 1); BARF();
        // p4: stage HA0(t+2) (A region consumed @p3); counted drain
        if (t + 2 < NT) STG_A1(t + 2, 0);
        BARF(); LGKM0(); MM1(1, 0);
        if (t + 2 < NT) { VMC4(); } else { VMC0(); }
        BARF();
    }

    const int crow = m0 + wq * 64 + fq * 4;
    const int ccol = n0 + wn * 64 + fr;
    #pragma unroll
    for (int m = 0; m < 4; m++)
        #pragma unroll
        for (int n = 0; n < 4; n++)
            #pragma unroll
            for (int rr = 0; rr < 4; rr++)
                C[(size_t)(crow + m*16 + rr) * N + ccol + n*16] = acc[m][n][rr];
#undef STG_A1
#undef STG_B1
#undef RD_A1
#undef RD_B1
#undef MM1
}

// --------- fused RMSNorm + RoPE + 16-token block-diagonal attention --------
__global__ __launch_bounds__(64) void attn_fused(const float* __restrict__ qkv,
                                                 const float* __restrict__ cosb,
                                                 const float* __restrict__ sinb,
                                                 const float* __restrict__ qw,
                                                 const float* __restrict__ kw,
                                                 unsigned short* __restrict__ out) {
    const int h    = blockIdx.x & (NH - 1);
    const int blk  = (blockIdx.x >> 4) & 127;
    const int b    = blockIdx.x >> 11;
    const int pos0 = blk * 16;
    const int kvh  = h >> 2;

    const int lane = threadIdx.x;
    const int r    = lane >> 2;
    const int qp   = lane & 3;
    const int d0   = qp * 16;

    __shared__ float qs[16][65];
    __shared__ float ks[16][65];
    __shared__ float vs[16][65];
    __shared__ float ps[16][17];

    const size_t rowb = ((size_t)(b * L_SEQ + pos0 + r)) * NQKV;
    const float* qptr = qkv + (rowb + h) * HD + d0;
    const float* kptr = qkv + (rowb + NH + kvh) * HD + d0;
    const float* vptr = qkv + (rowb + NH + NKV + kvh) * HD + d0;
    const size_t csrow = ((size_t)(b * L_SEQ + pos0 + r)) * HD + d0;

    float q[16], k[16], v[16], cs[16], sn[16];
    #pragma unroll
    for (int i = 0; i < 16; i += 4) {
        *(float4*)&q[i]  = *(const float4*)&qptr[i];
        *(float4*)&k[i]  = *(const float4*)&kptr[i];
        *(float4*)&v[i]  = *(const float4*)&vptr[i];
        *(float4*)&cs[i] = *(const float4*)&cosb[csrow + i];
        *(float4*)&sn[i] = *(const float4*)&sinb[csrow + i];
    }

    float sq = 0.f, sk = 0.f;
    #pragma unroll
    for (int i = 0; i < 16; i++) { sq += q[i]*q[i]; sk += k[i]*k[i]; }
    sq += __shfl_xor(sq, 1); sq += __shfl_xor(sq, 2);
    sk += __shfl_xor(sk, 1); sk += __shfl_xor(sk, 2);
    const float rq = rsqrtf(sq * (1.f / HD) + EPSV);
    const float rk = rsqrtf(sk * (1.f / HD) + EPSV);

    const float sgn = (qp < 2) ? -1.f : 1.f;
    #pragma unroll
    for (int i = 0; i < 16; i++) {
        float qn = q[i] * rq * qw[d0 + i];
        float kn = k[i] * rk * kw[d0 + i];
        float qo = __shfl_xor(qn, 2);
        float ko = __shfl_xor(kn, 2);
        qs[r][d0 + i] = qn * cs[i] + sgn * qo * sn[i];
        ks[r][d0 + i] = kn * cs[i] + sgn * ko * sn[i];
        vs[r][d0 + i] = v[i];
    }
    __syncthreads();

    float sc[4] = {0.f, 0.f, 0.f, 0.f};
    for (int d = 0; d < 64; d++) {
        const float qd = qs[r][d];
        sc[0] += qd * ks[qp     ][d];
        sc[1] += qd * ks[qp +  4][d];
        sc[2] += qd * ks[qp +  8][d];
        sc[3] += qd * ks[qp + 12][d];
    }
    #pragma unroll
    for (int cc = 0; cc < 4; cc++) {
        const int c = qp + cc * 4;
        sc[cc] = (c <= r) ? sc[cc] * 0.125f : -3.0e38f;
    }
    float mx = fmaxf(fmaxf(sc[0], sc[1]), fmaxf(sc[2], sc[3]));
    mx = fmaxf(mx, __shfl_xor(mx, 1));
    mx = fmaxf(mx, __shfl_xor(mx, 2));
    float e[4], sum = 0.f;
    #pragma unroll
    for (int cc = 0; cc < 4; cc++) { e[cc] = __expf(sc[cc] - mx); sum += e[cc]; }
    sum += __shfl_xor(sum, 1); sum += __shfl_xor(sum, 2);
    const float inv = 1.f / sum;
    #pragma unroll
    for (int cc = 0; cc < 4; cc++) ps[r][qp + cc * 4] = e[cc] * inv;
    __syncthreads();

    float o[16];
    #pragma unroll
    for (int i = 0; i < 16; i++) o[i] = 0.f;
    #pragma unroll
    for (int c = 0; c < 16; c++) {
        const float p = ps[r][c];
        #pragma unroll
        for (int i = 0; i < 16; i++) o[i] += p * vs[c][d0 + i];
    }

    __attribute__((aligned(16))) unsigned short ob[16];
    #pragma unroll
    for (int i = 0; i < 16; i++) ob[i] = f2b(o[i]);
    unsigned short* optr = out + (((size_t)(b * L_SEQ + pos0 + r) * NH + h) * HD) + d0;
    *(uint4*)optr       = *(uint4*)&ob[0];
    *((uint4*)optr + 1) = *(uint4*)&ob[8];
}

// ---------------------------------------------------------------------------
extern "C" void kernel_launch(void* const* d_in, const int* in_sizes, int n_in,
                              void* d_out, int out_size, void* d_ws, size_t ws_size,
                              hipStream_t stream) {
    const float* hid  = (const float*)d_in[0];
    const float* cosb = (const float*)d_in[2];
    const float* sinb = (const float*)d_in[3];
    const float* Wqkv = (const float*)d_in[4];
    const float* Wo   = (const float*)d_in[5];
    const float* qw   = (const float*)d_in[6];
    const float* kw   = (const float*)d_in[7];
    float* outp = (float*)d_out;

    char* ws = (char*)d_ws;
    unsigned short* Hb    = (unsigned short*)ws; ws += (size_t)M_ROWS * HID * 2;
    unsigned short* WqkvT = (unsigned short*)ws; ws += (size_t)QKV_N * HID * 2;
    unsigned short* WoT   = (unsigned short*)ws; ws += (size_t)HID * O_N * 2;
    float*          qkvf  = (float*)ws;          ws += (size_t)M_ROWS * QKV_N * 4;
    unsigned short* attnb = (unsigned short*)ws;

    {
        int n8 = (M_ROWS * HID) / 8;
        cvt_f32_bf16<<<(n8 + 255) / 256, 256, 0, stream>>>(hid, Hb, n8);
    }
    transpose_f32_bf16<<<dim3(QKV_N / 32, HID / 32), 256, 0, stream>>>(Wqkv, WqkvT, HID, QKV_N);
    transpose_f32_bf16<<<dim3(HID / 32, O_N / 32),  256, 0, stream>>>(Wo,   WoT,   O_N, HID);
    // qkv = H @ Wqkv   (4096 x 1536 x 4096): 256x128 tiles, 192 blocks
    gemm256x128_bf16<<<dim3((M_ROWS / 256) * (QKV_N / 128)), 512, 0, stream>>>(Hb, WqkvT, qkvf, M_ROWS, QKV_N, HID);
    // fused rmsnorm + rope + block-diag attention
    attn_fused<<<dim3(B_SZ * (L_SEQ / 16) * NH), 64, 0, stream>>>(qkvf, cosb, sinb, qw, kw, attnb);
    // out = attn @ Wo  (4096 x 4096 x 1024): 256x256 tiles, 256 blocks
    gemm256_bf16<<<dim3((M_ROWS / 256) * (HID / 256)), 512, 0, stream>>>(attnb, WoT, outp, M_ROWS, HID, O_N);
}

// Round 4
// 160.641 us; speedup vs baseline: 1.1908x; 1.0071x over previous
//
#include <hip/hip_runtime.h>
#include <hip/hip_bf16.h>
#include <cstdint>

// Problem constants (from reference)
#define B_SZ   2
#define L_SEQ  2048
#define HID    4096
#define NH     16
#define NKV    4
#define HD     64
#define NQKV   (NH + 2*NKV)      // 24
#define QKV_N  (NQKV*HD)         // 1536
#define O_N    (NH*HD)           // 1024
#define M_ROWS (B_SZ*L_SEQ)      // 4096
#define EPSV   1e-6f

typedef __bf16  bf16x8_t  __attribute__((ext_vector_type(8)));
typedef float   f32x4_t   __attribute__((ext_vector_type(4)));
typedef unsigned short ushort8_t __attribute__((ext_vector_type(8)));

__device__ __forceinline__ unsigned short f2b(float f) {
    union { float f; uint32_t u; } v; v.f = f;
    uint32_t r = v.u + 0x7FFFu + ((v.u >> 16) & 1u);   // RNE to bf16
    return (unsigned short)(r >> 16);
}
__device__ __forceinline__ float b2f(unsigned short u) {
    union { uint32_t u; float f; } v; v.u = ((uint32_t)u) << 16;
    return v.f;
}

__device__ __forceinline__ void gload_lds16(const void* g, void* l) {
    __builtin_amdgcn_global_load_lds(
        (__attribute__((address_space(1))) void*)(g),
        (__attribute__((address_space(3))) void*)(l),
        16, 0, 0);
}

#define BARF() do { asm volatile("" ::: "memory"); \
                    __builtin_amdgcn_s_barrier();  \
                    asm volatile("" ::: "memory"); } while (0)
#define LGKM0() do { asm volatile("s_waitcnt lgkmcnt(0)" ::: "memory"); \
                     __builtin_amdgcn_sched_barrier(0); } while (0)
#define VMC6()  asm volatile("s_waitcnt vmcnt(6)" ::: "memory")
#define VMC4()  asm volatile("s_waitcnt vmcnt(4)" ::: "memory")
#define VMC0()  asm volatile("s_waitcnt vmcnt(0)" ::: "memory")

// ---------------- fp32 -> bf16 elementwise (8 elems/thread) ----------------
__global__ __launch_bounds__(256) void cvt_f32_bf16(const float* __restrict__ in,
                                                    unsigned short* __restrict__ out,
                                                    int n8) {
    int i = blockIdx.x * 256 + threadIdx.x;
    if (i >= n8) return;
    const float4* p = (const float4*)(in + (size_t)i * 8);
    float4 a = p[0], b = p[1];
    ushort8_t o;
    o[0]=f2b(a.x); o[1]=f2b(a.y); o[2]=f2b(a.z); o[3]=f2b(a.w);
    o[4]=f2b(b.x); o[5]=f2b(b.y); o[6]=f2b(b.z); o[7]=f2b(b.w);
    *(ushort8_t*)(out + (size_t)i * 8) = o;
}

// ------------- transpose fp32 (R x C) -> bf16 (C x R) ----------------------
__global__ __launch_bounds__(256) void transpose_f32_bf16(const float* __restrict__ in,
                                                          unsigned short* __restrict__ out,
                                                          int R, int C) {
    __shared__ float t[32][33];
    const int c0 = blockIdx.x * 32;
    const int r0 = blockIdx.y * 32;
    const int tx = threadIdx.x & 31;
    const int ty = threadIdx.x >> 5;
    #pragma unroll
    for (int i = 0; i < 32; i += 8)
        t[ty + i][tx] = in[(size_t)(r0 + ty + i) * C + c0 + tx];
    __syncthreads();
    #pragma unroll
    for (int i = 0; i < 32; i += 8)
        out[(size_t)(c0 + ty + i) * R + r0 + tx] = f2b(t[tx][ty + i]);
}

// ===========================================================================
// GEMM 256x256, BK=64, 8 waves (2M x 4N), 4-phase counted-vmcnt schedule.
// LDS 128 KiB: buf s at s*32768 shorts; A [256][64] + B(+16384) [256][64].
// ===========================================================================
__global__ __launch_bounds__(512, 2) void gemm256_bf16(const unsigned short* __restrict__ A,
                                                       const unsigned short* __restrict__ Bt,
                                                       float* __restrict__ C,
                                                       int M, int N, int K) {
    __shared__ unsigned short smem[65536];   // 128 KiB

    const int tid  = threadIdx.x;
    const int lane = tid & 63;
    const int wave = tid >> 6;         // 0..7
    const int wr   = wave >> 2;        // 0..1  M-half (128 rows)
    const int wc   = wave & 3;         // 0..3  N-quarter (64 cols)
    const int fr   = lane & 15;
    const int fq   = lane >> 4;

    const int nbx = N >> 8;
    int bid = blockIdx.x;
    const int cpx = gridDim.x >> 3;
    bid = (bid & 7) * cpx + (bid >> 3);
    const int bx = bid % nbx, by = bid / nbx;
    const int m0 = by << 8, n0 = bx << 8;

    const int srow = tid >> 3;
    const int scs  = ((tid & 7) ^ (srow & 7)) << 3;
    const unsigned short* gA = A  + (size_t)(m0 + srow) * K + scs;
    const unsigned short* gB = Bt + (size_t)(n0 + srow) * K + scs;

    const int cx0 = ((fq)     ^ (fr & 7)) << 3;
    const int cx1 = ((4 | fq) ^ (fr & 7)) << 3;

    f32x4_t acc[8][4];
    #pragma unroll
    for (int m = 0; m < 8; m++)
        #pragma unroll
        for (int n = 0; n < 4; n++)
            acc[m][n] = (f32x4_t){0.f, 0.f, 0.f, 0.f};

    bf16x8_t aF[2][2];
    bf16x8_t bF[4][2];

#define STG_A2(T, H) { _Pragma("unroll") for (int q = 0; q < 2; ++q) \
    gload_lds16(gA + (size_t)((H)*128 + q*64) * K + ((size_t)(T) << 6), \
                &smem[(((T)&1)<<15) + ((H)*128 + q*64)*64 + tid*8]); }
#define STG_B2(T, H) { _Pragma("unroll") for (int q = 0; q < 2; ++q) \
    gload_lds16(gB + (size_t)((H)*128 + q*64) * K + ((size_t)(T) << 6), \
                &smem[(((T)&1)<<15) + 16384 + ((H)*128 + q*64)*64 + tid*8]); }
#define RD_B2(SB) { _Pragma("unroll") for (int nn = 0; nn < 4; ++nn) { \
    const int ro = (SB) + 16384 + (wc*64 + nn*16 + fr)*64; \
    bF[nn][0] = *(const bf16x8_t*)&smem[ro + cx0]; \
    bF[nn][1] = *(const bf16x8_t*)&smem[ro + cx1]; } }
#define RD_A2(SB, P) { _Pragma("unroll") for (int m2 = 0; m2 < 2; ++m2) { \
    const int ro = (SB) + (wr*128 + ((P)*2 + m2)*16 + fr)*64; \
    aF[m2][0] = *(const bf16x8_t*)&smem[ro + cx0]; \
    aF[m2][1] = *(const bf16x8_t*)&smem[ro + cx1]; } }
#define MM2(P) { __builtin_amdgcn_s_setprio(1); \
    _Pragma("unroll") for (int m2 = 0; m2 < 2; ++m2) \
    _Pragma("unroll") for (int nn = 0; nn < 4; ++nn) \
    _Pragma("unroll") for (int kk = 0; kk < 2; ++kk) \
        acc[(P)*2 + m2][nn] = __builtin_amdgcn_mfma_f32_16x16x32_bf16( \
            aF[m2][kk], bF[nn][kk], acc[(P)*2 + m2][nn], 0, 0, 0); \
    __builtin_amdgcn_s_setprio(0); }

    const int NT = K >> 6;
    STG_A2(0, 0); STG_A2(0, 1); STG_B2(0, 0); STG_B2(0, 1);
    STG_B2(1, 0); STG_B2(1, 1);
    VMC4();
    BARF();

    for (int t = 0; t < NT; ++t) {
        const int sb = (t & 1) << 15;
        RD_B2(sb); RD_A2(sb, 0);
        if (t + 1 < NT) STG_A2(t + 1, 0);
        BARF(); LGKM0(); MM2(0); BARF();
        RD_A2(sb, 1);
        if (t + 1 < NT) STG_A2(t + 1, 1);
        BARF(); LGKM0(); MM2(1); BARF();
        RD_A2(sb, 2);
        if (t + 2 < NT) STG_B2(t + 2, 0);
        BARF(); LGKM0(); MM2(2); BARF();
        RD_A2(sb, 3);
        if (t + 2 < NT) STG_B2(t + 2, 1);
        BARF(); LGKM0(); MM2(3);
        if (t + 2 < NT) { VMC4(); } else { VMC0(); }
        BARF();
    }

    const int crow = m0 + wr * 128 + fq * 4;
    const int ccol = n0 + wc * 64 + fr;
    #pragma unroll
    for (int m = 0; m < 8; m++)
        #pragma unroll
        for (int n = 0; n < 4; n++)
            #pragma unroll
            for (int rr = 0; rr < 4; rr++)
                C[(size_t)(crow + m*16 + rr) * N + ccol + n*16] = acc[m][n][rr];
#undef STG_A2
#undef STG_B2
#undef RD_B2
#undef RD_A2
#undef MM2
}

// ===========================================================================
// GEMM1: 256x128 tile, BK=64, 8 waves (4M x 2N, per-wave 64x64).
// TRIPLE-buffered LDS (3 x 48 KiB = 144 KiB), 2 phases/K-tile, 16 MFMA/phase.
// Staging: full tile t+2 (6 gloads) issued at p1(t); end-of-tile vmcnt(6)
// keeps t+2's loads in flight while guaranteeing t+1 landed (T4 counted).
// Output bf16.
// ===========================================================================
__global__ __launch_bounds__(512, 2) void gemm256x128_bf16(const unsigned short* __restrict__ A,
                                                           const unsigned short* __restrict__ Bt,
                                                           unsigned short* __restrict__ C,
                                                           int M, int N, int K) {
    __shared__ unsigned short smem[73728];   // 144 KiB, 3 bufs x 24576

    const int tid  = threadIdx.x;
    const int lane = tid & 63;
    const int wave = tid >> 6;         // 0..7
    const int wq   = wave >> 1;        // 0..3  M-quarter (64 rows)
    const int wn   = wave & 1;         // 0..1  N-half (64 cols)
    const int fr   = lane & 15;
    const int fq   = lane >> 4;

    const int nbx = N >> 7;
    int bid = blockIdx.x;
    const int cpx = gridDim.x >> 3;
    bid = (bid & 7) * cpx + (bid >> 3);
    const int bx = bid % nbx, by = bid / nbx;
    const int m0 = by << 8, n0 = bx << 7;

    const int srow = tid >> 3;
    const int scs  = ((tid & 7) ^ (srow & 7)) << 3;
    const unsigned short* gA = A  + (size_t)(m0 + srow) * K + scs;
    const unsigned short* gB = Bt + (size_t)(n0 + srow) * K + scs;

    const int cx0 = ((fq)     ^ (fr & 7)) << 3;
    const int cx1 = ((4 | fq) ^ (fr & 7)) << 3;

    f32x4_t acc[4][4];
    #pragma unroll
    for (int m = 0; m < 4; m++)
        #pragma unroll
        for (int n = 0; n < 4; n++)
            acc[m][n] = (f32x4_t){0.f, 0.f, 0.f, 0.f};

    bf16x8_t aF[4][2];    // all 4 mm fragments, live across both phases
    bf16x8_t bF[2][2];    // current nn pair

    // stage full tile T (A: 4 rounds, B: 2 rounds) into buf[T%3]
#define STG_T1(T) { const int pb = ((T)%3)*24576; \
    _Pragma("unroll") for (int q = 0; q < 4; ++q) \
        gload_lds16(gA + (size_t)(q*64)*K + ((size_t)(T) << 6), \
                    &smem[pb + q*4096 + tid*8]); \
    _Pragma("unroll") for (int q = 0; q < 2; ++q) \
        gload_lds16(gB + (size_t)(q*64)*K + ((size_t)(T) << 6), \
                    &smem[pb + 16384 + q*4096 + tid*8]); }
#define RD_A1(SB) { _Pragma("unroll") for (int mm = 0; mm < 4; ++mm) { \
    const int ro = (SB) + (wq*64 + mm*16 + fr)*64; \
    aF[mm][0] = *(const bf16x8_t*)&smem[ro + cx0]; \
    aF[mm][1] = *(const bf16x8_t*)&smem[ro + cx1]; } }
#define RD_B1(SB, NN) { _Pragma("unroll") for (int n2 = 0; n2 < 2; ++n2) { \
    const int ro = (SB) + 16384 + (wn*64 + ((NN) + n2)*16 + fr)*64; \
    bF[n2][0] = *(const bf16x8_t*)&smem[ro + cx0]; \
    bF[n2][1] = *(const bf16x8_t*)&smem[ro + cx1]; } }
#define MM1(NH_) { __builtin_amdgcn_s_setprio(1); \
    _Pragma("unroll") for (int mm = 0; mm < 4; ++mm) \
    _Pragma("unroll") for (int n2 = 0; n2 < 2; ++n2) \
    _Pragma("unroll") for (int kk = 0; kk < 2; ++kk) \
        acc[mm][(NH_)*2 + n2] = __builtin_amdgcn_mfma_f32_16x16x32_bf16( \
            aF[mm][kk], bF[n2][kk], acc[mm][(NH_)*2 + n2], 0, 0, 0); \
    __builtin_amdgcn_s_setprio(0); }

    const int NT = K >> 6;    // 64
    // prologue: stage tiles 0 and 1; wait tile 0 (tile 1's 6 loads in flight)
    STG_T1(0);
    STG_T1(1);
    VMC6();
    BARF();

    for (int t = 0; t < NT; ++t) {
        const int sb = (t % 3) * 24576;
        // p1: read all A fragments + B nn01; stage full tile t+2
        RD_A1(sb); RD_B1(sb, 0);
        if (t + 2 < NT) STG_T1(t + 2);
        BARF(); LGKM0(); MM1(0); BARF();
        // p2: read B nn23
        RD_B1(sb, 2);
        BARF(); LGKM0(); MM1(1);
        // end of tile: guarantee t+1 landed, keep t+2's 6 loads in flight
        if (t + 2 < NT) { VMC6(); } else if (t + 1 < NT) { VMC0(); }
        BARF();
    }

    const int crow = m0 + wq * 64 + fq * 4;
    const int ccol = n0 + wn * 64 + fr;
    #pragma unroll
    for (int m = 0; m < 4; m++)
        #pragma unroll
        for (int n = 0; n < 4; n++)
            #pragma unroll
            for (int rr = 0; rr < 4; rr++)
                C[(size_t)(crow + m*16 + rr) * N + ccol + n*16] = f2b(acc[m][n][rr]);
#undef STG_T1
#undef RD_A1
#undef RD_B1
#undef MM1
}

// --------- fused RMSNorm + RoPE + 16-token block-diagonal attention --------
// qkv input is bf16 now.
__global__ __launch_bounds__(64) void attn_fused(const unsigned short* __restrict__ qkv,
                                                 const float* __restrict__ cosb,
                                                 const float* __restrict__ sinb,
                                                 const float* __restrict__ qw,
                                                 const float* __restrict__ kw,
                                                 unsigned short* __restrict__ out) {
    const int h    = blockIdx.x & (NH - 1);
    const int blk  = (blockIdx.x >> 4) & 127;
    const int b    = blockIdx.x >> 11;
    const int pos0 = blk * 16;
    const int kvh  = h >> 2;

    const int lane = threadIdx.x;
    const int r    = lane >> 2;
    const int qp   = lane & 3;
    const int d0   = qp * 16;

    __shared__ float qs[16][65];
    __shared__ float ks[16][65];
    __shared__ float vs[16][65];
    __shared__ float ps[16][17];

    const size_t rowb = ((size_t)(b * L_SEQ + pos0 + r)) * NQKV;
    const unsigned short* qptr = qkv + (rowb + h) * HD + d0;
    const unsigned short* kptr = qkv + (rowb + NH + kvh) * HD + d0;
    const unsigned short* vptr = qkv + (rowb + NH + NKV + kvh) * HD + d0;
    const size_t csrow = ((size_t)(b * L_SEQ + pos0 + r)) * HD + d0;

    float q[16], k[16], v[16], cs[16], sn[16];
    {
        ushort8_t q0 = *(const ushort8_t*)&qptr[0], q1 = *(const ushort8_t*)&qptr[8];
        ushort8_t k0 = *(const ushort8_t*)&kptr[0], k1 = *(const ushort8_t*)&kptr[8];
        ushort8_t v0 = *(const ushort8_t*)&vptr[0], v1 = *(const ushort8_t*)&vptr[8];
        #pragma unroll
        for (int i = 0; i < 8; i++) {
            q[i] = b2f(q0[i]); q[i+8] = b2f(q1[i]);
            k[i] = b2f(k0[i]); k[i+8] = b2f(k1[i]);
            v[i] = b2f(v0[i]); v[i+8] = b2f(v1[i]);
        }
        #pragma unroll
        for (int i = 0; i < 16; i += 4) {
            *(float4*)&cs[i] = *(const float4*)&cosb[csrow + i];
            *(float4*)&sn[i] = *(const float4*)&sinb[csrow + i];
        }
    }

    float sq = 0.f, sk = 0.f;
    #pragma unroll
    for (int i = 0; i < 16; i++) { sq += q[i]*q[i]; sk += k[i]*k[i]; }
    sq += __shfl_xor(sq, 1); sq += __shfl_xor(sq, 2);
    sk += __shfl_xor(sk, 1); sk += __shfl_xor(sk, 2);
    const float rq = rsqrtf(sq * (1.f / HD) + EPSV);
    const float rk = rsqrtf(sk * (1.f / HD) + EPSV);

    const float sgn = (qp < 2) ? -1.f : 1.f;
    #pragma unroll
    for (int i = 0; i < 16; i++) {
        float qn = q[i] * rq * qw[d0 + i];
        float kn = k[i] * rk * kw[d0 + i];
        float qo = __shfl_xor(qn, 2);
        float ko = __shfl_xor(kn, 2);
        qs[r][d0 + i] = qn * cs[i] + sgn * qo * sn[i];
        ks[r][d0 + i] = kn * cs[i] + sgn * ko * sn[i];
        vs[r][d0 + i] = v[i];
    }
    __syncthreads();

    float sc[4] = {0.f, 0.f, 0.f, 0.f};
    for (int d = 0; d < 64; d++) {
        const float qd = qs[r][d];
        sc[0] += qd * ks[qp     ][d];
        sc[1] += qd * ks[qp +  4][d];
        sc[2] += qd * ks[qp +  8][d];
        sc[3] += qd * ks[qp + 12][d];
    }
    #pragma unroll
    for (int cc = 0; cc < 4; cc++) {
        const int c = qp + cc * 4;
        sc[cc] = (c <= r) ? sc[cc] * 0.125f : -3.0e38f;
    }
    float mx = fmaxf(fmaxf(sc[0], sc[1]), fmaxf(sc[2], sc[3]));
    mx = fmaxf(mx, __shfl_xor(mx, 1));
    mx = fmaxf(mx, __shfl_xor(mx, 2));
    float e[4], sum = 0.f;
    #pragma unroll
    for (int cc = 0; cc < 4; cc++) { e[cc] = __expf(sc[cc] - mx); sum += e[cc]; }
    sum += __shfl_xor(sum, 1); sum += __shfl_xor(sum, 2);
    const float inv = 1.f / sum;
    #pragma unroll
    for (int cc = 0; cc < 4; cc++) ps[r][qp + cc * 4] = e[cc] * inv;
    __syncthreads();

    float o[16];
    #pragma unroll
    for (int i = 0; i < 16; i++) o[i] = 0.f;
    #pragma unroll
    for (int c = 0; c < 16; c++) {
        const float p = ps[r][c];
        #pragma unroll
        for (int i = 0; i < 16; i++) o[i] += p * vs[c][d0 + i];
    }

    __attribute__((aligned(16))) unsigned short ob[16];
    #pragma unroll
    for (int i = 0; i < 16; i++) ob[i] = f2b(o[i]);
    unsigned short* optr = out + (((size_t)(b * L_SEQ + pos0 + r) * NH + h) * HD) + d0;
    *(uint4*)optr       = *(uint4*)&ob[0];
    *((uint4*)optr + 1) = *(uint4*)&ob[8];
}

// ---------------------------------------------------------------------------
extern "C" void kernel_launch(void* const* d_in, const int* in_sizes, int n_in,
                              void* d_out, int out_size, void* d_ws, size_t ws_size,
                              hipStream_t stream) {
    const float* hid  = (const float*)d_in[0];
    const float* cosb = (const float*)d_in[2];
    const float* sinb = (const float*)d_in[3];
    const float* Wqkv = (const float*)d_in[4];
    const float* Wo   = (const float*)d_in[5];
    const float* qw   = (const float*)d_in[6];
    const float* kw   = (const float*)d_in[7];
    float* outp = (float*)d_out;

    char* ws = (char*)d_ws;
    unsigned short* Hb    = (unsigned short*)ws; ws += (size_t)M_ROWS * HID * 2;
    unsigned short* WqkvT = (unsigned short*)ws; ws += (size_t)QKV_N * HID * 2;
    unsigned short* WoT   = (unsigned short*)ws; ws += (size_t)HID * O_N * 2;
    unsigned short* qkvb  = (unsigned short*)ws; ws += (size_t)M_ROWS * QKV_N * 2;
    unsigned short* attnb = (unsigned short*)ws;

    {
        int n8 = (M_ROWS * HID) / 8;
        cvt_f32_bf16<<<(n8 + 255) / 256, 256, 0, stream>>>(hid, Hb, n8);
    }
    transpose_f32_bf16<<<dim3(QKV_N / 32, HID / 32), 256, 0, stream>>>(Wqkv, WqkvT, HID, QKV_N);
    transpose_f32_bf16<<<dim3(HID / 32, O_N / 32),  256, 0, stream>>>(Wo,   WoT,   O_N, HID);
    // qkv = H @ Wqkv (4096 x 1536 x 4096): 256x128, triple-buf 2-phase, bf16 out
    gemm256x128_bf16<<<dim3((M_ROWS / 256) * (QKV_N / 128)), 512, 0, stream>>>(Hb, WqkvT, qkvb, M_ROWS, QKV_N, HID);
    // fused rmsnorm + rope + block-diag attention (bf16 in/out)
    attn_fused<<<dim3(B_SZ * (L_SEQ / 16) * NH), 64, 0, stream>>>(qkvb, cosb, sinb, qw, kw, attnb);
    // out = attn @ Wo (4096 x 4096 x 1024): 256x256 4-phase
    gemm256_bf16<<<dim3((M_ROWS / 256) * (HID / 256)), 512, 0, stream>>>(attnb, WoT, outp, M_ROWS, HID, O_N);
}

// Round 5
// 158.795 us; speedup vs baseline: 1.2046x; 1.0116x over previous
//
#include <hip/hip_runtime.h>
#include <hip/hip_bf16.h>
#include <cstdint>

// Problem constants (from reference)
#define B_SZ   2
#define L_SEQ  2048
#define HID    4096
#define NH     16
#define NKV    4
#define HD     64
#define NQKV   (NH + 2*NKV)      // 24
#define QKV_N  (NQKV*HD)         // 1536
#define O_N    (NH*HD)           // 1024
#define M_ROWS (B_SZ*L_SEQ)      // 4096
#define EPSV   1e-6f

typedef __bf16  bf16x8_t  __attribute__((ext_vector_type(8)));
typedef float   f32x4_t   __attribute__((ext_vector_type(4)));
typedef unsigned short ushort8_t __attribute__((ext_vector_type(8)));

__device__ __forceinline__ unsigned short f2b(float f) {
    union { float f; uint32_t u; } v; v.f = f;
    uint32_t r = v.u + 0x7FFFu + ((v.u >> 16) & 1u);   // RNE to bf16
    return (unsigned short)(r >> 16);
}
__device__ __forceinline__ float b2f(unsigned short u) {
    union { uint32_t u; float f; } v; v.u = ((uint32_t)u) << 16;
    return v.f;
}

__device__ __forceinline__ void gload_lds16(const void* g, void* l) {
    __builtin_amdgcn_global_load_lds(
        (__attribute__((address_space(1))) void*)(g),
        (__attribute__((address_space(3))) void*)(l),
        16, 0, 0);
}

#define BARF() do { asm volatile("" ::: "memory"); \
                    __builtin_amdgcn_s_barrier();  \
                    asm volatile("" ::: "memory"); } while (0)
// plain lgkm wait (no sched_barrier: ds_reads here are compiler loads, the
// compiler tracks their deps; pinning the scheduler regresses — m141)
#define LGKMW() asm volatile("s_waitcnt lgkmcnt(0)" ::: "memory")
#define VMC6()  asm volatile("s_waitcnt vmcnt(6)" ::: "memory")
#define VMC4()  asm volatile("s_waitcnt vmcnt(4)" ::: "memory")
#define VMC0()  asm volatile("s_waitcnt vmcnt(0)" ::: "memory")

// ---------------- fp32 -> bf16 elementwise (8 elems/thread) ----------------
__global__ __launch_bounds__(256) void cvt_f32_bf16(const float* __restrict__ in,
                                                    unsigned short* __restrict__ out,
                                                    int n8) {
    int i = blockIdx.x * 256 + threadIdx.x;
    if (i >= n8) return;
    const float4* p = (const float4*)(in + (size_t)i * 8);
    float4 a = p[0], b = p[1];
    ushort8_t o;
    o[0]=f2b(a.x); o[1]=f2b(a.y); o[2]=f2b(a.z); o[3]=f2b(a.w);
    o[4]=f2b(b.x); o[5]=f2b(b.y); o[6]=f2b(b.z); o[7]=f2b(b.w);
    *(ushort8_t*)(out + (size_t)i * 8) = o;
}

// ------------- transpose fp32 (R x C) -> bf16 (C x R) ----------------------
__global__ __launch_bounds__(256) void transpose_f32_bf16(const float* __restrict__ in,
                                                          unsigned short* __restrict__ out,
                                                          int R, int C) {
    __shared__ float t[32][33];
    const int c0 = blockIdx.x * 32;
    const int r0 = blockIdx.y * 32;
    const int tx = threadIdx.x & 31;
    const int ty = threadIdx.x >> 5;
    #pragma unroll
    for (int i = 0; i < 32; i += 8)
        t[ty + i][tx] = in[(size_t)(r0 + ty + i) * C + c0 + tx];
    __syncthreads();
    #pragma unroll
    for (int i = 0; i < 32; i += 8)
        out[(size_t)(c0 + ty + i) * R + r0 + tx] = f2b(t[tx][ty + i]);
}

// ===========================================================================
// GEMM2 256x256, BK=64, 8 waves (2M x 4N, per-wave 128x64), 4 balanced
// phases/K-tile: one C-quadrant (mm-half x kk) per phase, 4-8 ds_read_b128 +
// 16 MFMA each (m201 recipe). Counted vmcnt(4)/tile.
// LDS 128 KiB: buf s at s*32768; A [256][64] + B(+16384) [256][64], chunk^row
// swizzle both sides.
// Staging: A(t+1) halves @p1,p2 (other buffer); B(t+2) @p4 (own B region,
// k1-reads retired at p3).
// ===========================================================================
__global__ __launch_bounds__(512, 2) void gemm256_bf16(const unsigned short* __restrict__ A,
                                                       const unsigned short* __restrict__ Bt,
                                                       float* __restrict__ C,
                                                       int M, int N, int K) {
    __shared__ unsigned short smem[65536];   // 128 KiB

    const int tid  = threadIdx.x;
    const int lane = tid & 63;
    const int wave = tid >> 6;         // 0..7
    const int wr   = wave >> 2;        // 0..1  M-half (128 rows)
    const int wc   = wave & 3;         // 0..3  N-quarter (64 cols)
    const int fr   = lane & 15;
    const int fq   = lane >> 4;

    const int nbx = N >> 8;
    int bid = blockIdx.x;
    const int cpx = gridDim.x >> 3;
    bid = (bid & 7) * cpx + (bid >> 3);
    const int bx = bid % nbx, by = bid / nbx;
    const int m0 = by << 8, n0 = bx << 8;

    const int srow = tid >> 3;
    const int scs  = ((tid & 7) ^ (srow & 7)) << 3;
    const unsigned short* gA = A  + (size_t)(m0 + srow) * K + scs;
    const unsigned short* gB = Bt + (size_t)(n0 + srow) * K + scs;

    const int cx0 = ((fq)     ^ (fr & 7)) << 3;   // kk=0 chunk
    const int cx1 = ((4 | fq) ^ (fr & 7)) << 3;   // kk=1 chunk

    f32x4_t acc[8][4];
    #pragma unroll
    for (int m = 0; m < 8; m++)
        #pragma unroll
        for (int n = 0; n < 4; n++)
            acc[m][n] = (f32x4_t){0.f, 0.f, 0.f, 0.f};

    bf16x8_t aF[4];    // per-phase A fragments (one mm-half, one kk)
    bf16x8_t bFk[4];   // current-kk B fragments (live 2 phases)

#define STG_A2(T, H) { _Pragma("unroll") for (int q = 0; q < 2; ++q) \
    gload_lds16(gA + (size_t)((H)*128 + q*64) * K + ((size_t)(T) << 6), \
                &smem[(((T)&1)<<15) + ((H)*128 + q*64)*64 + tid*8]); }
#define STG_B2(T, H) { _Pragma("unroll") for (int q = 0; q < 2; ++q) \
    gload_lds16(gB + (size_t)((H)*128 + q*64) * K + ((size_t)(T) << 6), \
                &smem[(((T)&1)<<15) + 16384 + ((H)*128 + q*64)*64 + tid*8]); }
#define RD_A2(SB, H, KX) { _Pragma("unroll") for (int mm = 0; mm < 4; ++mm) { \
    const int ro = (SB) + (wr*128 + (H)*64 + mm*16 + fr)*64; \
    aF[mm] = *(const bf16x8_t*)&smem[ro + (KX)]; } }
#define RD_B2(SB, KX) { _Pragma("unroll") for (int nn = 0; nn < 4; ++nn) { \
    const int ro = (SB) + 16384 + (wc*64 + nn*16 + fr)*64; \
    bFk[nn] = *(const bf16x8_t*)&smem[ro + (KX)]; } }
#define MM2(H) { __builtin_amdgcn_s_setprio(1); \
    _Pragma("unroll") for (int mm = 0; mm < 4; ++mm) \
    _Pragma("unroll") for (int nn = 0; nn < 4; ++nn) \
        acc[(H)*4 + mm][nn] = __builtin_amdgcn_mfma_f32_16x16x32_bf16( \
            aF[mm], bFk[nn], acc[(H)*4 + mm][nn], 0, 0, 0); \
    __builtin_amdgcn_s_setprio(0); }

    const int NT = K >> 6;
    // prologue: tile0 complete + tile1 B (tile1 A staged during tile0)
    STG_A2(0, 0); STG_A2(0, 1); STG_B2(0, 0); STG_B2(0, 1);
    STG_B2(1, 0); STG_B2(1, 1);
    VMC4();                      // tile0 landed; tile1-B's 4 in flight
    BARF();

    for (int t = 0; t < NT; ++t) {
        const int sb = (t & 1) << 15;
        // p1: A(h0,k0) + B(k0) = 8 reads; stage A(t+1) h0
        RD_A2(sb, 0, cx0); RD_B2(sb, cx0);
        if (t + 1 < NT) STG_A2(t + 1, 0);
        BARF(); LGKMW(); MM2(0); BARF();
        // p2: A(h1,k0) = 4 reads; stage A(t+1) h1
        RD_A2(sb, 1, cx0);
        if (t + 1 < NT) STG_A2(t + 1, 1);
        BARF(); LGKMW(); MM2(1); BARF();
        // p3: A(h0,k1) + B(k1) = 8 reads
        RD_A2(sb, 0, cx1); RD_B2(sb, cx1);
        BARF(); LGKMW(); MM2(0); BARF();
        // p4: A(h1,k1) = 4 reads; stage B(t+2) (B reads retired at p3)
        RD_A2(sb, 1, cx1);
        if (t + 2 < NT) { STG_B2(t + 2, 0); STG_B2(t + 2, 1); }
        BARF(); LGKMW(); MM2(1);
        if (t + 2 < NT) { VMC4(); } else { VMC0(); }
        BARF();
    }

    const int crow = m0 + wr * 128 + fq * 4;
    const int ccol = n0 + wc * 64 + fr;
    #pragma unroll
    for (int m = 0; m < 8; m++)
        #pragma unroll
        for (int n = 0; n < 4; n++)
            #pragma unroll
            for (int rr = 0; rr < 4; rr++)
                C[(size_t)(crow + m*16 + rr) * N + ccol + n*16] = acc[m][n][rr];
#undef STG_A2
#undef STG_B2
#undef RD_A2
#undef RD_B2
#undef MM2
}

// ===========================================================================
// GEMM1: 256x128 tile, BK=64, 8 waves (4M x 2N, per-wave 64x64).
// TRIPLE-buffered LDS (3 x 48 KiB), 2 balanced phases/K-tile (kk-split):
// 8 ds_read_b128 + 16 MFMA per phase. Staging of tile t+2 split 3+3 across
// the phases; vmcnt(6) per tile. Output bf16.
// ===========================================================================
__global__ __launch_bounds__(512, 2) void gemm256x128_bf16(const unsigned short* __restrict__ A,
                                                           const unsigned short* __restrict__ Bt,
                                                           unsigned short* __restrict__ C,
                                                           int M, int N, int K) {
    __shared__ unsigned short smem[73728];   // 144 KiB, 3 bufs x 24576

    const int tid  = threadIdx.x;
    const int lane = tid & 63;
    const int wave = tid >> 6;         // 0..7
    const int wq   = wave >> 1;        // 0..3  M-quarter (64 rows)
    const int wn   = wave & 1;         // 0..1  N-half (64 cols)
    const int fr   = lane & 15;
    const int fq   = lane >> 4;

    const int nbx = N >> 7;
    int bid = blockIdx.x;
    const int cpx = gridDim.x >> 3;
    bid = (bid & 7) * cpx + (bid >> 3);
    const int bx = bid % nbx, by = bid / nbx;
    const int m0 = by << 8, n0 = bx << 7;

    const int srow = tid >> 3;
    const int scs  = ((tid & 7) ^ (srow & 7)) << 3;
    const unsigned short* gA = A  + (size_t)(m0 + srow) * K + scs;
    const unsigned short* gB = Bt + (size_t)(n0 + srow) * K + scs;

    const int cx0 = ((fq)     ^ (fr & 7)) << 3;
    const int cx1 = ((4 | fq) ^ (fr & 7)) << 3;

    f32x4_t acc[4][4];
    #pragma unroll
    for (int m = 0; m < 4; m++)
        #pragma unroll
        for (int n = 0; n < 4; n++)
            acc[m][n] = (f32x4_t){0.f, 0.f, 0.f, 0.f};

    bf16x8_t aF[4];    // per-phase (one kk)
    bf16x8_t bF[4];

    // stage tile T into buf[T%3]: part a = A rounds 0-2, part b = A round 3
    // + B rounds 0-1 (3 gloads each)
#define STG_T1a(T) { const int pb = ((T)%3)*24576; \
    _Pragma("unroll") for (int q = 0; q < 3; ++q) \
        gload_lds16(gA + (size_t)(q*64)*K + ((size_t)(T) << 6), \
                    &smem[pb + q*4096 + tid*8]); }
#define STG_T1b(T) { const int pb = ((T)%3)*24576; \
    gload_lds16(gA + (size_t)(3*64)*K + ((size_t)(T) << 6), \
                &smem[pb + 3*4096 + tid*8]); \
    _Pragma("unroll") for (int q = 0; q < 2; ++q) \
        gload_lds16(gB + (size_t)(q*64)*K + ((size_t)(T) << 6), \
                    &smem[pb + 16384 + q*4096 + tid*8]); }
#define RD_A1(SB, KX) { _Pragma("unroll") for (int mm = 0; mm < 4; ++mm) { \
    const int ro = (SB) + (wq*64 + mm*16 + fr)*64; \
    aF[mm] = *(const bf16x8_t*)&smem[ro + (KX)]; } }
#define RD_B1(SB, KX) { _Pragma("unroll") for (int nn = 0; nn < 4; ++nn) { \
    const int ro = (SB) + 16384 + (wn*64 + nn*16 + fr)*64; \
    bF[nn] = *(const bf16x8_t*)&smem[ro + (KX)]; } }
#define MM1() { __builtin_amdgcn_s_setprio(1); \
    _Pragma("unroll") for (int mm = 0; mm < 4; ++mm) \
    _Pragma("unroll") for (int nn = 0; nn < 4; ++nn) \
        acc[mm][nn] = __builtin_amdgcn_mfma_f32_16x16x32_bf16( \
            aF[mm], bF[nn], acc[mm][nn], 0, 0, 0); \
    __builtin_amdgcn_s_setprio(0); }

    const int NT = K >> 6;    // 64
    // prologue: stage tiles 0 and 1; wait tile 0 (tile 1's 6 loads in flight)
    STG_T1a(0); STG_T1b(0);
    STG_T1a(1); STG_T1b(1);
    VMC6();
    BARF();

    for (int t = 0; t < NT; ++t) {
        const int sb = (t % 3) * 24576;
        // p1: kk=0 quadrant (8 reads, 16 MFMA); stage t+2 part a
        RD_A1(sb, cx0); RD_B1(sb, cx0);
        if (t + 2 < NT) STG_T1a(t + 2);
        BARF(); LGKMW(); MM1(); BARF();
        // p2: kk=1 quadrant; stage t+2 part b
        RD_A1(sb, cx1); RD_B1(sb, cx1);
        if (t + 2 < NT) STG_T1b(t + 2);
        BARF(); LGKMW(); MM1();
        if (t + 2 < NT) { VMC6(); } else if (t + 1 < NT) { VMC0(); }
        BARF();
    }

    const int crow = m0 + wq * 64 + fq * 4;
    const int ccol = n0 + wn * 64 + fr;
    #pragma unroll
    for (int m = 0; m < 4; m++)
        #pragma unroll
        for (int n = 0; n < 4; n++)
            #pragma unroll
            for (int rr = 0; rr < 4; rr++)
                C[(size_t)(crow + m*16 + rr) * N + ccol + n*16] = f2b(acc[m][n][rr]);
#undef STG_T1a
#undef STG_T1b
#undef RD_A1
#undef RD_B1
#undef MM1
}

// --------- fused RMSNorm + RoPE + 16-token block-diagonal attention --------
__global__ __launch_bounds__(64) void attn_fused(const unsigned short* __restrict__ qkv,
                                                 const float* __restrict__ cosb,
                                                 const float* __restrict__ sinb,
                                                 const float* __restrict__ qw,
                                                 const float* __restrict__ kw,
                                                 unsigned short* __restrict__ out) {
    const int h    = blockIdx.x & (NH - 1);
    const int blk  = (blockIdx.x >> 4) & 127;
    const int b    = blockIdx.x >> 11;
    const int pos0 = blk * 16;
    const int kvh  = h >> 2;

    const int lane = threadIdx.x;
    const int r    = lane >> 2;
    const int qp   = lane & 3;
    const int d0   = qp * 16;

    __shared__ float qs[16][65];
    __shared__ float ks[16][65];
    __shared__ float vs[16][65];
    __shared__ float ps[16][17];

    const size_t rowb = ((size_t)(b * L_SEQ + pos0 + r)) * NQKV;
    const unsigned short* qptr = qkv + (rowb + h) * HD + d0;
    const unsigned short* kptr = qkv + (rowb + NH + kvh) * HD + d0;
    const unsigned short* vptr = qkv + (rowb + NH + NKV + kvh) * HD + d0;
    const size_t csrow = ((size_t)(b * L_SEQ + pos0 + r)) * HD + d0;

    float q[16], k[16], v[16], cs[16], sn[16];
    {
        ushort8_t q0 = *(const ushort8_t*)&qptr[0], q1 = *(const ushort8_t*)&qptr[8];
        ushort8_t k0 = *(const ushort8_t*)&kptr[0], k1 = *(const ushort8_t*)&kptr[8];
        ushort8_t v0 = *(const ushort8_t*)&vptr[0], v1 = *(const ushort8_t*)&vptr[8];
        #pragma unroll
        for (int i = 0; i < 8; i++) {
            q[i] = b2f(q0[i]); q[i+8] = b2f(q1[i]);
            k[i] = b2f(k0[i]); k[i+8] = b2f(k1[i]);
            v[i] = b2f(v0[i]); v[i+8] = b2f(v1[i]);
        }
        #pragma unroll
        for (int i = 0; i < 16; i += 4) {
            *(float4*)&cs[i] = *(const float4*)&cosb[csrow + i];
            *(float4*)&sn[i] = *(const float4*)&sinb[csrow + i];
        }
    }

    float sq = 0.f, sk = 0.f;
    #pragma unroll
    for (int i = 0; i < 16; i++) { sq += q[i]*q[i]; sk += k[i]*k[i]; }
    sq += __shfl_xor(sq, 1); sq += __shfl_xor(sq, 2);
    sk += __shfl_xor(sk, 1); sk += __shfl_xor(sk, 2);
    const float rq = rsqrtf(sq * (1.f / HD) + EPSV);
    const float rk = rsqrtf(sk * (1.f / HD) + EPSV);

    const float sgn = (qp < 2) ? -1.f : 1.f;
    #pragma unroll
    for (int i = 0; i < 16; i++) {
        float qn = q[i] * rq * qw[d0 + i];
        float kn = k[i] * rk * kw[d0 + i];
        float qo = __shfl_xor(qn, 2);
        float ko = __shfl_xor(kn, 2);
        qs[r][d0 + i] = qn * cs[i] + sgn * qo * sn[i];
        ks[r][d0 + i] = kn * cs[i] + sgn * ko * sn[i];
        vs[r][d0 + i] = v[i];
    }
    __syncthreads();

    float sc[4] = {0.f, 0.f, 0.f, 0.f};
    for (int d = 0; d < 64; d++) {
        const float qd = qs[r][d];
        sc[0] += qd * ks[qp     ][d];
        sc[1] += qd * ks[qp +  4][d];
        sc[2] += qd * ks[qp +  8][d];
        sc[3] += qd * ks[qp + 12][d];
    }
    #pragma unroll
    for (int cc = 0; cc < 4; cc++) {
        const int c = qp + cc * 4;
        sc[cc] = (c <= r) ? sc[cc] * 0.125f : -3.0e38f;
    }
    float mx = fmaxf(fmaxf(sc[0], sc[1]), fmaxf(sc[2], sc[3]));
    mx = fmaxf(mx, __shfl_xor(mx, 1));
    mx = fmaxf(mx, __shfl_xor(mx, 2));
    float e[4], sum = 0.f;
    #pragma unroll
    for (int cc = 0; cc < 4; cc++) { e[cc] = __expf(sc[cc] - mx); sum += e[cc]; }
    sum += __shfl_xor(sum, 1); sum += __shfl_xor(sum, 2);
    const float inv = 1.f / sum;
    #pragma unroll
    for (int cc = 0; cc < 4; cc++) ps[r][qp + cc * 4] = e[cc] * inv;
    __syncthreads();

    float o[16];
    #pragma unroll
    for (int i = 0; i < 16; i++) o[i] = 0.f;
    #pragma unroll
    for (int c = 0; c < 16; c++) {
        const float p = ps[r][c];
        #pragma unroll
        for (int i = 0; i < 16; i++) o[i] += p * vs[c][d0 + i];
    }

    __attribute__((aligned(16))) unsigned short ob[16];
    #pragma unroll
    for (int i = 0; i < 16; i++) ob[i] = f2b(o[i]);
    unsigned short* optr = out + (((size_t)(b * L_SEQ + pos0 + r) * NH + h) * HD) + d0;
    *(uint4*)optr       = *(uint4*)&ob[0];
    *((uint4*)optr + 1) = *(uint4*)&ob[8];
}

// ---------------------------------------------------------------------------
extern "C" void kernel_launch(void* const* d_in, const int* in_sizes, int n_in,
                              void* d_out, int out_size, void* d_ws, size_t ws_size,
                              hipStream_t stream) {
    const float* hid  = (const float*)d_in[0];
    const float* cosb = (const float*)d_in[2];
    const float* sinb = (const float*)d_in[3];
    const float* Wqkv = (const float*)d_in[4];
    const float* Wo   = (const float*)d_in[5];
    const float* qw   = (const float*)d_in[6];
    const float* kw   = (const float*)d_in[7];
    float* outp = (float*)d_out;

    char* ws = (char*)d_ws;
    unsigned short* Hb    = (unsigned short*)ws; ws += (size_t)M_ROWS * HID * 2;
    unsigned short* WqkvT = (unsigned short*)ws; ws += (size_t)QKV_N * HID * 2;
    unsigned short* WoT   = (unsigned short*)ws; ws += (size_t)HID * O_N * 2;
    unsigned short* qkvb  = (unsigned short*)ws; ws += (size_t)M_ROWS * QKV_N * 2;
    unsigned short* attnb = (unsigned short*)ws;

    {
        int n8 = (M_ROWS * HID) / 8;
        cvt_f32_bf16<<<(n8 + 255) / 256, 256, 0, stream>>>(hid, Hb, n8);
    }
    transpose_f32_bf16<<<dim3(QKV_N / 32, HID / 32), 256, 0, stream>>>(Wqkv, WqkvT, HID, QKV_N);
    transpose_f32_bf16<<<dim3(HID / 32, O_N / 32),  256, 0, stream>>>(Wo,   WoT,   O_N, HID);
    // qkv = H @ Wqkv (4096 x 1536 x 4096): 256x128, balanced 2-phase, bf16 out
    gemm256x128_bf16<<<dim3((M_ROWS / 256) * (QKV_N / 128)), 512, 0, stream>>>(Hb, WqkvT, qkvb, M_ROWS, QKV_N, HID);
    // fused rmsnorm + rope + block-diag attention (bf16 in/out)
    attn_fused<<<dim3(B_SZ * (L_SEQ / 16) * NH), 64, 0, stream>>>(qkvb, cosb, sinb, qw, kw, attnb);
    // out = attn @ Wo (4096 x 4096 x 1024): 256x256 balanced 4-phase
    gemm256_bf16<<<dim3((M_ROWS / 256) * (HID / 256)), 512, 0, stream>>>(attnb, WoT, outp, M_ROWS, HID, O_N);
}

// Round 6
// 151.399 us; speedup vs baseline: 1.2634x; 1.0489x over previous
//
#include <hip/hip_runtime.h>
#include <hip/hip_bf16.h>
#include <cstdint>

// Problem constants (from reference)
#define B_SZ   2
#define L_SEQ  2048
#define HID    4096
#define NH     16
#define NKV    4
#define HD     64
#define NQKV   (NH + 2*NKV)      // 24
#define QKV_N  (NQKV*HD)         // 1536
#define O_N    (NH*HD)           // 1024
#define M_ROWS (B_SZ*L_SEQ)      // 4096
#define EPSV   1e-6f

typedef __bf16  bf16x8_t  __attribute__((ext_vector_type(8)));
typedef float   f32x4_t   __attribute__((ext_vector_type(4)));
typedef unsigned short ushort8_t __attribute__((ext_vector_type(8)));

__device__ __forceinline__ unsigned short f2b(float f) {
    union { float f; uint32_t u; } v; v.f = f;
    uint32_t r = v.u + 0x7FFFu + ((v.u >> 16) & 1u);   // RNE to bf16
    return (unsigned short)(r >> 16);
}
__device__ __forceinline__ float b2f(unsigned short u) {
    union { uint32_t u; float f; } v; v.u = ((uint32_t)u) << 16;
    return v.f;
}

__device__ __forceinline__ void gload_lds16(const void* g, void* l) {
    __builtin_amdgcn_global_load_lds(
        (__attribute__((address_space(1))) void*)(g),
        (__attribute__((address_space(3))) void*)(l),
        16, 0, 0);
}

#define BARF() do { asm volatile("" ::: "memory"); \
                    __builtin_amdgcn_s_barrier();  \
                    asm volatile("" ::: "memory"); } while (0)

template <int N> __device__ __forceinline__ void vmcnt_wait() {
    if constexpr (N == 5)      asm volatile("s_waitcnt vmcnt(5)" ::: "memory");
    else if constexpr (N == 6) asm volatile("s_waitcnt vmcnt(6)" ::: "memory");
    else                       asm volatile("s_waitcnt vmcnt(0)" ::: "memory");
}

// ---------------- fp32 -> bf16 elementwise (8 elems/thread) ----------------
__global__ __launch_bounds__(256) void cvt_f32_bf16(const float* __restrict__ in,
                                                    unsigned short* __restrict__ out,
                                                    int n8) {
    int i = blockIdx.x * 256 + threadIdx.x;
    if (i >= n8) return;
    const float4* p = (const float4*)(in + (size_t)i * 8);
    float4 a = p[0], b = p[1];
    ushort8_t o;
    o[0]=f2b(a.x); o[1]=f2b(a.y); o[2]=f2b(a.z); o[3]=f2b(a.w);
    o[4]=f2b(b.x); o[5]=f2b(b.y); o[6]=f2b(b.z); o[7]=f2b(b.w);
    *(ushort8_t*)(out + (size_t)i * 8) = o;
}

// ------------- transpose fp32 (R x C) -> bf16 (C x R) ----------------------
__global__ __launch_bounds__(256) void transpose_f32_bf16(const float* __restrict__ in,
                                                          unsigned short* __restrict__ out,
                                                          int R, int C) {
    __shared__ float t[32][33];
    const int c0 = blockIdx.x * 32;
    const int r0 = blockIdx.y * 32;
    const int tx = threadIdx.x & 31;
    const int ty = threadIdx.x >> 5;
    #pragma unroll
    for (int i = 0; i < 32; i += 8)
        t[ty + i][tx] = in[(size_t)(r0 + ty + i) * C + c0 + tx];
    __syncthreads();
    #pragma unroll
    for (int i = 0; i < 32; i += 8)
        out[(size_t)(c0 + ty + i) * R + r0 + tx] = f2b(t[tx][ty + i]);
}

// ===========================================================================
// Single-barrier triple-buffered MFMA GEMM template.
//   C[M,N] = A[M,K] * Bt[N,K]^T, bf16 in, OutT out.
//   8 waves as NWM x NWN, per-wave WM x WN output, BK=64, kk-split in 2.
//   LDS: 3 buffers x (BM+BN)*64 shorts. Staging of tile t+2 issued inside
//   tile t; exactly ONE s_barrier + ONE counted vmcnt per K-tile (triple
//   buffering removes all intra-tile hazards; waves desync within a tile so
//   ds_read and MFMA pipes overlap across waves).
//   Hazard proof: stage(t) targets buf[(t+2)%3], never read during t/t+1;
//   a wave passes barrier(t+1) only after its tile-t ds_reads completed
//   (lgkm before its MFMAs), so stage(t+1)->buf[t%3] is safe.
// ===========================================================================
template <int BM, int BN, int NWM, int NWN, bool OBF16, typename OutT>
__global__ __launch_bounds__(512, 2)
void gemm_sb(const unsigned short* __restrict__ A,
             const unsigned short* __restrict__ Bt,
             OutT* __restrict__ C, int M, int N, int K) {
    constexpr int WM   = BM / NWM;
    constexpr int WN   = BN / NWN;
    constexpr int AF   = WM / 16;
    constexpr int BF   = WN / 16;
    constexpr int BUF  = (BM + BN) * 64;   // shorts per buffer
    constexpr int AR   = BM / 64;          // A staging rounds (512thr x 16B)
    constexpr int BR   = BN / 64;          // B staging rounds
    constexpr int RNDS = AR + BR;          // gloads/thread/tile

    __shared__ unsigned short smem[3 * BUF];

    const int tid  = threadIdx.x;
    const int lane = tid & 63;
    const int wave = tid >> 6;
    const int wm   = wave / NWN;
    const int wn   = wave % NWN;
    const int fr   = lane & 15;
    const int fq   = lane >> 4;

    // XCD-aware bijective swizzle (gridDim.x % 8 == 0)
    const int nbx = N / BN;
    int bid = blockIdx.x;
    const int cpx = gridDim.x >> 3;
    bid = (bid & 7) * cpx + (bid >> 3);
    const int bx = bid % nbx, by = bid / nbx;
    const int m0 = by * BM, n0 = bx * BN;

    const int srow = tid >> 3;
    const int scs  = ((tid & 7) ^ (srow & 7)) << 3;   // pre-swizzled src k-off
    const unsigned short* gA = A  + (size_t)(m0 + srow) * K + scs;
    const unsigned short* gB = Bt + (size_t)(n0 + srow) * K + scs;

    const int cx0 = ((fq)     ^ (fr & 7)) << 3;       // kk=0 chunk
    const int cx1 = ((4 | fq) ^ (fr & 7)) << 3;       // kk=1 chunk

    f32x4_t acc[AF][BF];
    #pragma unroll
    for (int m = 0; m < AF; m++)
        #pragma unroll
        for (int n = 0; n < BF; n++)
            acc[m][n] = (f32x4_t){0.f, 0.f, 0.f, 0.f};

    const int NT = K >> 6;

#define STAGE_SB(T) { const int pb = ((T) % 3) * BUF; \
    _Pragma("unroll") for (int q = 0; q < AR; ++q) \
        gload_lds16(gA + (size_t)(q*64)*K + ((size_t)(T) << 6), \
                    &smem[pb + q*4096 + tid*8]); \
    _Pragma("unroll") for (int q = 0; q < BR; ++q) \
        gload_lds16(gB + (size_t)(q*64)*K + ((size_t)(T) << 6), \
                    &smem[pb + BM*64 + q*4096 + tid*8]); }

    // prologue: stage tiles 0,1; tile0 landed, tile1's RNDS loads in flight
    STAGE_SB(0);
    STAGE_SB(1);
    vmcnt_wait<RNDS>();

    for (int t = 0; t < NT; ++t) {
        const int sb = (t % 3) * BUF;
        BARF();   // the ONLY barrier per tile

        bf16x8_t a0[AF], b0[BF];
        #pragma unroll
        for (int mm = 0; mm < AF; ++mm)
            a0[mm] = *(const bf16x8_t*)&smem[sb + (wm*WM + mm*16 + fr)*64 + cx0];
        #pragma unroll
        for (int nn = 0; nn < BF; ++nn)
            b0[nn] = *(const bf16x8_t*)&smem[sb + BM*64 + (wn*WN + nn*16 + fr)*64 + cx0];

        if (t + 2 < NT) STAGE_SB(t + 2);   // writes buf[(t+2)%3]: no hazard

        __builtin_amdgcn_s_setprio(1);
        #pragma unroll
        for (int mm = 0; mm < AF; ++mm)
            #pragma unroll
            for (int nn = 0; nn < BF; ++nn)
                acc[mm][nn] = __builtin_amdgcn_mfma_f32_16x16x32_bf16(
                    a0[mm], b0[nn], acc[mm][nn], 0, 0, 0);
        __builtin_amdgcn_s_setprio(0);

        bf16x8_t a1[AF], b1[BF];
        #pragma unroll
        for (int mm = 0; mm < AF; ++mm)
            a1[mm] = *(const bf16x8_t*)&smem[sb + (wm*WM + mm*16 + fr)*64 + cx1];
        #pragma unroll
        for (int nn = 0; nn < BF; ++nn)
            b1[nn] = *(const bf16x8_t*)&smem[sb + BM*64 + (wn*WN + nn*16 + fr)*64 + cx1];

        __builtin_amdgcn_s_setprio(1);
        #pragma unroll
        for (int mm = 0; mm < AF; ++mm)
            #pragma unroll
            for (int nn = 0; nn < BF; ++nn)
                acc[mm][nn] = __builtin_amdgcn_mfma_f32_16x16x32_bf16(
                    a1[mm], b1[nn], acc[mm][nn], 0, 0, 0);
        __builtin_amdgcn_s_setprio(0);

        // counted drain: tile t+1 guaranteed landed; t+2's RNDS stay in flight
        if (t + 2 < NT)      { vmcnt_wait<RNDS>(); }
        else if (t + 1 < NT) { vmcnt_wait<0>(); }
    }
#undef STAGE_SB

    // C/D layout (m89-verified): col = lane&15, row = (lane>>4)*4 + reg
    const int crow = m0 + wm * WM + fq * 4;
    const int ccol = n0 + wn * WN + fr;
    #pragma unroll
    for (int m = 0; m < AF; m++)
        #pragma unroll
        for (int n = 0; n < BF; n++)
            #pragma unroll
            for (int rr = 0; rr < 4; rr++) {
                const size_t idx = (size_t)(crow + m*16 + rr) * N + ccol + n*16;
                if constexpr (OBF16) C[idx] = (OutT)f2b(acc[m][n][rr]);
                else                 C[idx] = (OutT)acc[m][n][rr];
            }
}

// --------- fused RMSNorm + RoPE + 16-token block-diagonal attention --------
__global__ __launch_bounds__(64) void attn_fused(const unsigned short* __restrict__ qkv,
                                                 const float* __restrict__ cosb,
                                                 const float* __restrict__ sinb,
                                                 const float* __restrict__ qw,
                                                 const float* __restrict__ kw,
                                                 unsigned short* __restrict__ out) {
    const int h    = blockIdx.x & (NH - 1);
    const int blk  = (blockIdx.x >> 4) & 127;
    const int b    = blockIdx.x >> 11;
    const int pos0 = blk * 16;
    const int kvh  = h >> 2;

    const int lane = threadIdx.x;
    const int r    = lane >> 2;
    const int qp   = lane & 3;
    const int d0   = qp * 16;

    __shared__ float qs[16][65];
    __shared__ float ks[16][65];
    __shared__ float vs[16][65];
    __shared__ float ps[16][17];

    const size_t rowb = ((size_t)(b * L_SEQ + pos0 + r)) * NQKV;
    const unsigned short* qptr = qkv + (rowb + h) * HD + d0;
    const unsigned short* kptr = qkv + (rowb + NH + kvh) * HD + d0;
    const unsigned short* vptr = qkv + (rowb + NH + NKV + kvh) * HD + d0;
    const size_t csrow = ((size_t)(b * L_SEQ + pos0 + r)) * HD + d0;

    float q[16], k[16], v[16], cs[16], sn[16];
    {
        ushort8_t q0 = *(const ushort8_t*)&qptr[0], q1 = *(const ushort8_t*)&qptr[8];
        ushort8_t k0 = *(const ushort8_t*)&kptr[0], k1 = *(const ushort8_t*)&kptr[8];
        ushort8_t v0 = *(const ushort8_t*)&vptr[0], v1 = *(const ushort8_t*)&vptr[8];
        #pragma unroll
        for (int i = 0; i < 8; i++) {
            q[i] = b2f(q0[i]); q[i+8] = b2f(q1[i]);
            k[i] = b2f(k0[i]); k[i+8] = b2f(k1[i]);
            v[i] = b2f(v0[i]); v[i+8] = b2f(v1[i]);
        }
        #pragma unroll
        for (int i = 0; i < 16; i += 4) {
            *(float4*)&cs[i] = *(const float4*)&cosb[csrow + i];
            *(float4*)&sn[i] = *(const float4*)&sinb[csrow + i];
        }
    }

    float sq = 0.f, sk = 0.f;
    #pragma unroll
    for (int i = 0; i < 16; i++) { sq += q[i]*q[i]; sk += k[i]*k[i]; }
    sq += __shfl_xor(sq, 1); sq += __shfl_xor(sq, 2);
    sk += __shfl_xor(sk, 1); sk += __shfl_xor(sk, 2);
    const float rq = rsqrtf(sq * (1.f / HD) + EPSV);
    const float rk = rsqrtf(sk * (1.f / HD) + EPSV);

    const float sgn = (qp < 2) ? -1.f : 1.f;
    #pragma unroll
    for (int i = 0; i < 16; i++) {
        float qn = q[i] * rq * qw[d0 + i];
        float kn = k[i] * rk * kw[d0 + i];
        float qo = __shfl_xor(qn, 2);
        float ko = __shfl_xor(kn, 2);
        qs[r][d0 + i] = qn * cs[i] + sgn * qo * sn[i];
        ks[r][d0 + i] = kn * cs[i] + sgn * ko * sn[i];
        vs[r][d0 + i] = v[i];
    }
    __syncthreads();

    float sc[4] = {0.f, 0.f, 0.f, 0.f};
    for (int d = 0; d < 64; d++) {
        const float qd = qs[r][d];
        sc[0] += qd * ks[qp     ][d];
        sc[1] += qd * ks[qp +  4][d];
        sc[2] += qd * ks[qp +  8][d];
        sc[3] += qd * ks[qp + 12][d];
    }
    #pragma unroll
    for (int cc = 0; cc < 4; cc++) {
        const int c = qp + cc * 4;
        sc[cc] = (c <= r) ? sc[cc] * 0.125f : -3.0e38f;
    }
    float mx = fmaxf(fmaxf(sc[0], sc[1]), fmaxf(sc[2], sc[3]));
    mx = fmaxf(mx, __shfl_xor(mx, 1));
    mx = fmaxf(mx, __shfl_xor(mx, 2));
    float e[4], sum = 0.f;
    #pragma unroll
    for (int cc = 0; cc < 4; cc++) { e[cc] = __expf(sc[cc] - mx); sum += e[cc]; }
    sum += __shfl_xor(sum, 1); sum += __shfl_xor(sum, 2);
    const float inv = 1.f / sum;
    #pragma unroll
    for (int cc = 0; cc < 4; cc++) ps[r][qp + cc * 4] = e[cc] * inv;
    __syncthreads();

    float o[16];
    #pragma unroll
    for (int i = 0; i < 16; i++) o[i] = 0.f;
    #pragma unroll
    for (int c = 0; c < 16; c++) {
        const float p = ps[r][c];
        #pragma unroll
        for (int i = 0; i < 16; i++) o[i] += p * vs[c][d0 + i];
    }

    __attribute__((aligned(16))) unsigned short ob[16];
    #pragma unroll
    for (int i = 0; i < 16; i++) ob[i] = f2b(o[i]);
    unsigned short* optr = out + (((size_t)(b * L_SEQ + pos0 + r) * NH + h) * HD) + d0;
    *(uint4*)optr       = *(uint4*)&ob[0];
    *((uint4*)optr + 1) = *(uint4*)&ob[8];
}

// ---------------------------------------------------------------------------
extern "C" void kernel_launch(void* const* d_in, const int* in_sizes, int n_in,
                              void* d_out, int out_size, void* d_ws, size_t ws_size,
                              hipStream_t stream) {
    const float* hid  = (const float*)d_in[0];
    const float* cosb = (const float*)d_in[2];
    const float* sinb = (const float*)d_in[3];
    const float* Wqkv = (const float*)d_in[4];
    const float* Wo   = (const float*)d_in[5];
    const float* qw   = (const float*)d_in[6];
    const float* kw   = (const float*)d_in[7];
    float* outp = (float*)d_out;

    char* ws = (char*)d_ws;
    unsigned short* Hb    = (unsigned short*)ws; ws += (size_t)M_ROWS * HID * 2;
    unsigned short* WqkvT = (unsigned short*)ws; ws += (size_t)QKV_N * HID * 2;
    unsigned short* WoT   = (unsigned short*)ws; ws += (size_t)HID * O_N * 2;
    unsigned short* qkvb  = (unsigned short*)ws; ws += (size_t)M_ROWS * QKV_N * 2;
    unsigned short* attnb = (unsigned short*)ws;

    {
        int n8 = (M_ROWS * HID) / 8;
        cvt_f32_bf16<<<(n8 + 255) / 256, 256, 0, stream>>>(hid, Hb, n8);
    }
    transpose_f32_bf16<<<dim3(QKV_N / 32, HID / 32), 256, 0, stream>>>(Wqkv, WqkvT, HID, QKV_N);
    transpose_f32_bf16<<<dim3(HID / 32, O_N / 32),  256, 0, stream>>>(Wo,   WoT,   O_N, HID);

    // GEMM1: qkv = H @ Wqkv (4096 x 1536 x 4096)
    //   128x192 tiles -> 32x8 = 256 blocks (1/CU), waves 2Mx4N (64x48/wave),
    //   LDS 3x40KB, single barrier + vmcnt(5) per K-tile
    gemm_sb<128, 192, 2, 4, true, unsigned short>
        <<<dim3((M_ROWS / 128) * (QKV_N / 192)), 512, 0, stream>>>
        (Hb, WqkvT, qkvb, M_ROWS, QKV_N, HID);

    // fused rmsnorm + rope + block-diag attention (bf16 in/out)
    attn_fused<<<dim3(B_SZ * (L_SEQ / 16) * NH), 64, 0, stream>>>(qkvb, cosb, sinb, qw, kw, attnb);

    // GEMM2: out = attn @ Wo (4096 x 4096 x 1024)
    //   256x128 tiles -> 16x32 = 512 blocks (2 seq blocks/CU), waves 4Mx2N
    //   (64x64/wave), LDS 3x48KB, single barrier + vmcnt(6) per K-tile
    gemm_sb<256, 128, 4, 2, false, float>
        <<<dim3((M_ROWS / 256) * (HID / 128)), 512, 0, stream>>>
        (attnb, WoT, outp, M_ROWS, HID, O_N);
}

// Round 7
// 143.895 us; speedup vs baseline: 1.3293x; 1.0521x over previous
//
#include <hip/hip_runtime.h>
#include <hip/hip_bf16.h>
#include <cstdint>

// Problem constants (from reference)
#define B_SZ   2
#define L_SEQ  2048
#define HID    4096
#define NH     16
#define NKV    4
#define HD     64
#define NQKV   (NH + 2*NKV)      // 24
#define QKV_N  (NQKV*HD)         // 1536
#define O_N    (NH*HD)           // 1024
#define M_ROWS (B_SZ*L_SEQ)      // 4096
#define EPSV   1e-6f

typedef __bf16  bf16x8_t  __attribute__((ext_vector_type(8)));
typedef float   f32x4_t   __attribute__((ext_vector_type(4)));
typedef unsigned short ushort8_t __attribute__((ext_vector_type(8)));

__device__ __forceinline__ unsigned short f2b(float f) {
    union { float f; uint32_t u; } v; v.f = f;
    uint32_t r = v.u + 0x7FFFu + ((v.u >> 16) & 1u);   // RNE to bf16
    return (unsigned short)(r >> 16);
}
__device__ __forceinline__ float b2f(unsigned short u) {
    union { uint32_t u; float f; } v; v.u = ((uint32_t)u) << 16;
    return v.f;
}

__device__ __forceinline__ void gload_lds16(const void* g, void* l) {
    __builtin_amdgcn_global_load_lds(
        (__attribute__((address_space(1))) void*)(g),
        (__attribute__((address_space(3))) void*)(l),
        16, 0, 0);
}

#define BARF() do { asm volatile("" ::: "memory"); \
                    __builtin_amdgcn_s_barrier();  \
                    asm volatile("" ::: "memory"); } while (0)

template <int N> __device__ __forceinline__ void vmcnt_wait() {
    if constexpr (N == 4)       asm volatile("s_waitcnt vmcnt(4)"  ::: "memory");
    else if constexpr (N == 5)  asm volatile("s_waitcnt vmcnt(5)"  ::: "memory");
    else if constexpr (N == 6)  asm volatile("s_waitcnt vmcnt(6)"  ::: "memory");
    else if constexpr (N == 8)  asm volatile("s_waitcnt vmcnt(8)"  ::: "memory");
    else if constexpr (N == 10) asm volatile("s_waitcnt vmcnt(10)" ::: "memory");
    else if constexpr (N == 12) asm volatile("s_waitcnt vmcnt(12)" ::: "memory");
    else                        asm volatile("s_waitcnt vmcnt(0)"  ::: "memory");
}

// ---------------- fp32 -> bf16 elementwise (8 elems/thread) ----------------
__global__ __launch_bounds__(256) void cvt_f32_bf16(const float* __restrict__ in,
                                                    unsigned short* __restrict__ out,
                                                    int n8) {
    int i = blockIdx.x * 256 + threadIdx.x;
    if (i >= n8) return;
    const float4* p = (const float4*)(in + (size_t)i * 8);
    float4 a = p[0], b = p[1];
    ushort8_t o;
    o[0]=f2b(a.x); o[1]=f2b(a.y); o[2]=f2b(a.z); o[3]=f2b(a.w);
    o[4]=f2b(b.x); o[5]=f2b(b.y); o[6]=f2b(b.z); o[7]=f2b(b.w);
    *(ushort8_t*)(out + (size_t)i * 8) = o;
}

// ------------- transpose fp32 (R x C) -> bf16 (C x R) ----------------------
__global__ __launch_bounds__(256) void transpose_f32_bf16(const float* __restrict__ in,
                                                          unsigned short* __restrict__ out,
                                                          int R, int C) {
    __shared__ float t[32][33];
    const int c0 = blockIdx.x * 32;
    const int r0 = blockIdx.y * 32;
    const int tx = threadIdx.x & 31;
    const int ty = threadIdx.x >> 5;
    #pragma unroll
    for (int i = 0; i < 32; i += 8)
        t[ty + i][tx] = in[(size_t)(r0 + ty + i) * C + c0 + tx];
    __syncthreads();
    #pragma unroll
    for (int i = 0; i < 32; i += 8)
        out[(size_t)(c0 + ty + i) * R + r0 + tx] = f2b(t[tx][ty + i]);
}

// ===========================================================================
// Single-barrier multi-buffered MFMA GEMM template.
//   C[M,N] = A[M,K] * Bt[N,K]^T, bf16 in, OutT out.
//   8 waves as NWM x NWN, per-wave WM x WN, one barrier + one counted vmcnt
//   per K-tile. NBUF LDS buffers; stage(t+NBUF-1) issued during tile t.
//   Hazard proof: stage(t) targets buf[(t+NBUF-1)%NBUF], never read during
//   tiles t..t+NBUF-2; a wave passes barrier(t+1) only after its tile-t
//   ds_reads completed (lgkm before its MFMAs), so no read-overwrite race.
//   In-order vmcnt: wait<(NBUF-2)*RNDS> at end of tile t retires everything
//   older than stages {t+2..t+NBUF-1}, i.e. guarantees tile t+1 landed.
//   T2 swizzle (both-sides involution): BK=64 -> chunk^(row&7) on 128B rows;
//   BK=32 -> chunk^((row>>1)&3) on 64B rows (2 rows per 128B bank line).
// ===========================================================================
template <int BM, int BN, int BK, int NBUF, int NWM, int NWN, bool OBF16, typename OutT>
__global__ __launch_bounds__(512, 2)
void gemm_sb(const unsigned short* __restrict__ A,
             const unsigned short* __restrict__ Bt,
             OutT* __restrict__ C, int M, int N, int K) {
    constexpr int WM    = BM / NWM;
    constexpr int WN    = BN / NWN;
    constexpr int AF    = WM / 16;
    constexpr int BF    = WN / 16;
    constexpr int KK    = BK / 32;         // 16x16x32 MFMAs per tile-k
    constexpr int BUF   = (BM + BN) * BK;  // shorts per buffer
    constexpr int ROWS  = 4096 / BK;       // rows covered per staging round
    constexpr int AR    = BM / ROWS;
    constexpr int BR    = BN / ROWS;
    constexpr int RNDS  = AR + BR;         // gloads/thread/tile
    constexpr int DEPTH = NBUF - 2;        // extra tiles in flight past t+1

    __shared__ unsigned short smem[NBUF * BUF];

    const int tid  = threadIdx.x;
    const int lane = tid & 63;
    const int wave = tid >> 6;
    const int wm   = wave / NWN;
    const int wn   = wave % NWN;
    const int fr   = lane & 15;
    const int fq   = lane >> 4;

    // XCD-aware bijective swizzle (gridDim.x % 8 == 0)
    const int nbx = N / BN;
    int bid = blockIdx.x;
    const int cpx = gridDim.x >> 3;
    bid = (bid & 7) * cpx + (bid >> 3);
    const int bx = bid % nbx, by = bid / nbx;
    const int m0 = by * BM, n0 = bx * BN;

    // staging address (pre-swizzled source; LDS dest stays linear)
    const int srow = tid / (BK / 8);                       // 8 thr/row @BK64, 4 @BK32
    const int sch  = tid & (BK / 8 - 1);
    const int ssw  = (BK == 64) ? (srow & 7) : ((srow >> 1) & 3);
    const int scs  = (sch ^ ssw) << 3;
    const unsigned short* gA = A  + (size_t)(m0 + srow) * K + scs;
    const unsigned short* gB = Bt + (size_t)(n0 + srow) * K + scs;

    // fragment-read swizzle (frag-row base is a multiple of 16 -> phase = f(fr))
    const int frsw = (BK == 64) ? (fr & 7) : ((fr >> 1) & 3);

    f32x4_t acc[AF][BF];
    #pragma unroll
    for (int m = 0; m < AF; m++)
        #pragma unroll
        for (int n = 0; n < BF; n++)
            acc[m][n] = (f32x4_t){0.f, 0.f, 0.f, 0.f};

    const int NT = K / BK;

    auto STAGE = [&](int T) {
        const int pb = (T % NBUF) * BUF;
        #pragma unroll
        for (int q = 0; q < AR; ++q)
            gload_lds16(gA + (size_t)(q * ROWS) * K + (size_t)T * BK,
                        &smem[pb + q * 4096 + tid * 8]);
        #pragma unroll
        for (int q = 0; q < BR; ++q)
            gload_lds16(gB + (size_t)(q * ROWS) * K + (size_t)T * BK,
                        &smem[pb + BM * BK + q * 4096 + tid * 8]);
    };

    // prologue: stage tiles 0..NBUF-2; tile0 landed, rest in flight
    #pragma unroll
    for (int pt = 0; pt < NBUF - 1; ++pt) STAGE(pt);
    vmcnt_wait<DEPTH * RNDS>();

    for (int t = 0; t < NT; ++t) {
        const int sb = (t % NBUF) * BUF;
        BARF();   // the ONLY barrier per tile

        #pragma unroll
        for (int kk = 0; kk < KK; ++kk) {
            const int cxk = (((kk * 4 + fq) ^ frsw)) << 3;
            bf16x8_t aF[AF], bF[BF];
            #pragma unroll
            for (int mm = 0; mm < AF; ++mm)
                aF[mm] = *(const bf16x8_t*)&smem[sb + (wm*WM + mm*16 + fr)*BK + cxk];
            #pragma unroll
            for (int nn = 0; nn < BF; ++nn)
                bF[nn] = *(const bf16x8_t*)&smem[sb + BM*BK + (wn*WN + nn*16 + fr)*BK + cxk];

            if (kk == 0 && t + NBUF - 1 < NT) STAGE(t + NBUF - 1);

            __builtin_amdgcn_s_setprio(1);
            #pragma unroll
            for (int mm = 0; mm < AF; ++mm)
                #pragma unroll
                for (int nn = 0; nn < BF; ++nn)
                    acc[mm][nn] = __builtin_amdgcn_mfma_f32_16x16x32_bf16(
                        aF[mm], bF[nn], acc[mm][nn], 0, 0, 0);
            __builtin_amdgcn_s_setprio(0);
        }

        // counted drain: guarantee t+1 landed; deeper stages stay in flight
        if constexpr (DEPTH == 2) {
            if (t + 3 < NT)      { vmcnt_wait<2 * RNDS>(); }
            else if (t + 2 < NT) { vmcnt_wait<RNDS>(); }
            else if (t + 1 < NT) { vmcnt_wait<0>(); }
        } else {
            if (t + 2 < NT)      { vmcnt_wait<RNDS>(); }
            else if (t + 1 < NT) { vmcnt_wait<0>(); }
        }
    }

    // C/D layout (m89-verified): col = lane&15, row = (lane>>4)*4 + reg
    const int crow = m0 + wm * WM + fq * 4;
    const int ccol = n0 + wn * WN + fr;
    #pragma unroll
    for (int m = 0; m < AF; m++)
        #pragma unroll
        for (int n = 0; n < BF; n++)
            #pragma unroll
            for (int rr = 0; rr < 4; rr++) {
                const size_t idx = (size_t)(crow + m*16 + rr) * N + ccol + n*16;
                if constexpr (OBF16) C[idx] = (OutT)f2b(acc[m][n][rr]);
                else                 C[idx] = (OutT)acc[m][n][rr];
            }
}

// --------- fused RMSNorm + RoPE + 16-token block-diagonal attention --------
__global__ __launch_bounds__(64) void attn_fused(const unsigned short* __restrict__ qkv,
                                                 const float* __restrict__ cosb,
                                                 const float* __restrict__ sinb,
                                                 const float* __restrict__ qw,
                                                 const float* __restrict__ kw,
                                                 unsigned short* __restrict__ out) {
    const int h    = blockIdx.x & (NH - 1);
    const int blk  = (blockIdx.x >> 4) & 127;
    const int b    = blockIdx.x >> 11;
    const int pos0 = blk * 16;
    const int kvh  = h >> 2;

    const int lane = threadIdx.x;
    const int r    = lane >> 2;
    const int qp   = lane & 3;
    const int d0   = qp * 16;

    __shared__ float qs[16][65];
    __shared__ float ks[16][65];
    __shared__ float vs[16][65];
    __shared__ float ps[16][17];

    const size_t rowb = ((size_t)(b * L_SEQ + pos0 + r)) * NQKV;
    const unsigned short* qptr = qkv + (rowb + h) * HD + d0;
    const unsigned short* kptr = qkv + (rowb + NH + kvh) * HD + d0;
    const unsigned short* vptr = qkv + (rowb + NH + NKV + kvh) * HD + d0;
    const size_t csrow = ((size_t)(b * L_SEQ + pos0 + r)) * HD + d0;

    float q[16], k[16], v[16], cs[16], sn[16];
    {
        ushort8_t q0 = *(const ushort8_t*)&qptr[0], q1 = *(const ushort8_t*)&qptr[8];
        ushort8_t k0 = *(const ushort8_t*)&kptr[0], k1 = *(const ushort8_t*)&kptr[8];
        ushort8_t v0 = *(const ushort8_t*)&vptr[0], v1 = *(const ushort8_t*)&vptr[8];
        #pragma unroll
        for (int i = 0; i < 8; i++) {
            q[i] = b2f(q0[i]); q[i+8] = b2f(q1[i]);
            k[i] = b2f(k0[i]); k[i+8] = b2f(k1[i]);
            v[i] = b2f(v0[i]); v[i+8] = b2f(v1[i]);
        }
        #pragma unroll
        for (int i = 0; i < 16; i += 4) {
            *(float4*)&cs[i] = *(const float4*)&cosb[csrow + i];
            *(float4*)&sn[i] = *(const float4*)&sinb[csrow + i];
        }
    }

    float sq = 0.f, sk = 0.f;
    #pragma unroll
    for (int i = 0; i < 16; i++) { sq += q[i]*q[i]; sk += k[i]*k[i]; }
    sq += __shfl_xor(sq, 1); sq += __shfl_xor(sq, 2);
    sk += __shfl_xor(sk, 1); sk += __shfl_xor(sk, 2);
    const float rq = rsqrtf(sq * (1.f / HD) + EPSV);
    const float rk = rsqrtf(sk * (1.f / HD) + EPSV);

    const float sgn = (qp < 2) ? -1.f : 1.f;
    #pragma unroll
    for (int i = 0; i < 16; i++) {
        float qn = q[i] * rq * qw[d0 + i];
        float kn = k[i] * rk * kw[d0 + i];
        float qo = __shfl_xor(qn, 2);
        float ko = __shfl_xor(kn, 2);
        qs[r][d0 + i] = qn * cs[i] + sgn * qo * sn[i];
        ks[r][d0 + i] = kn * cs[i] + sgn * ko * sn[i];
        vs[r][d0 + i] = v[i];
    }
    __syncthreads();

    float sc[4] = {0.f, 0.f, 0.f, 0.f};
    for (int d = 0; d < 64; d++) {
        const float qd = qs[r][d];
        sc[0] += qd * ks[qp     ][d];
        sc[1] += qd * ks[qp +  4][d];
        sc[2] += qd * ks[qp +  8][d];
        sc[3] += qd * ks[qp + 12][d];
    }
    #pragma unroll
    for (int cc = 0; cc < 4; cc++) {
        const int c = qp + cc * 4;
        sc[cc] = (c <= r) ? sc[cc] * 0.125f : -3.0e38f;
    }
    float mx = fmaxf(fmaxf(sc[0], sc[1]), fmaxf(sc[2], sc[3]));
    mx = fmaxf(mx, __shfl_xor(mx, 1));
    mx = fmaxf(mx, __shfl_xor(mx, 2));
    float e[4], sum = 0.f;
    #pragma unroll
    for (int cc = 0; cc < 4; cc++) { e[cc] = __expf(sc[cc] - mx); sum += e[cc]; }
    sum += __shfl_xor(sum, 1); sum += __shfl_xor(sum, 2);
    const float inv = 1.f / sum;
    #pragma unroll
    for (int cc = 0; cc < 4; cc++) ps[r][qp + cc * 4] = e[cc] * inv;
    __syncthreads();

    float o[16];
    #pragma unroll
    for (int i = 0; i < 16; i++) o[i] = 0.f;
    #pragma unroll
    for (int c = 0; c < 16; c++) {
        const float p = ps[r][c];
        #pragma unroll
        for (int i = 0; i < 16; i++) o[i] += p * vs[c][d0 + i];
    }

    __attribute__((aligned(16))) unsigned short ob[16];
    #pragma unroll
    for (int i = 0; i < 16; i++) ob[i] = f2b(o[i]);
    unsigned short* optr = out + (((size_t)(b * L_SEQ + pos0 + r) * NH + h) * HD) + d0;
    *(uint4*)optr       = *(uint4*)&ob[0];
    *((uint4*)optr + 1) = *(uint4*)&ob[8];
}

// ---------------------------------------------------------------------------
extern "C" void kernel_launch(void* const* d_in, const int* in_sizes, int n_in,
                              void* d_out, int out_size, void* d_ws, size_t ws_size,
                              hipStream_t stream) {
    const float* hid  = (const float*)d_in[0];
    const float* cosb = (const float*)d_in[2];
    const float* sinb = (const float*)d_in[3];
    const float* Wqkv = (const float*)d_in[4];
    const float* Wo   = (const float*)d_in[5];
    const float* qw   = (const float*)d_in[6];
    const float* kw   = (const float*)d_in[7];
    float* outp = (float*)d_out;

    char* ws = (char*)d_ws;
    unsigned short* Hb    = (unsigned short*)ws; ws += (size_t)M_ROWS * HID * 2;
    unsigned short* WqkvT = (unsigned short*)ws; ws += (size_t)QKV_N * HID * 2;
    unsigned short* WoT   = (unsigned short*)ws; ws += (size_t)HID * O_N * 2;
    unsigned short* qkvb  = (unsigned short*)ws; ws += (size_t)M_ROWS * QKV_N * 2;
    unsigned short* attnb = (unsigned short*)ws;

    {
        int n8 = (M_ROWS * HID) / 8;
        cvt_f32_bf16<<<(n8 + 255) / 256, 256, 0, stream>>>(hid, Hb, n8);
    }
    transpose_f32_bf16<<<dim3(QKV_N / 32, HID / 32), 256, 0, stream>>>(Wqkv, WqkvT, HID, QKV_N);
    transpose_f32_bf16<<<dim3(HID / 32, O_N / 32),  256, 0, stream>>>(Wo,   WoT,   O_N, HID);

    // GEMM1 (unchanged from round 6): qkv = H @ Wqkv (4096 x 1536 x 4096)
    //   128x192 tiles, BK=64, 3 buffers (120KB), 256 blocks (1/CU),
    //   waves 2Mx4N (64x48), single barrier + vmcnt(5) per tile
    gemm_sb<128, 192, 64, 3, 2, 4, true, unsigned short>
        <<<dim3((M_ROWS / 128) * (QKV_N / 192)), 512, 0, stream>>>
        (Hb, WqkvT, qkvb, M_ROWS, QKV_N, HID);

    // fused rmsnorm + rope + block-diag attention (bf16 in/out)
    attn_fused<<<dim3(B_SZ * (L_SEQ / 16) * NH), 64, 0, stream>>>(qkvb, cosb, sinb, qw, kw, attnb);

    // GEMM2 (new): out = attn @ Wo (4096 x 4096 x 1024)
    //   256x256 tiles, BK=32, 4 buffers (128KB), 256 blocks (1/CU),
    //   waves 2Mx4N (128x64, intensity 42.7), single barrier + vmcnt(8)/tile
    gemm_sb<256, 256, 32, 4, 2, 4, false, float>
        <<<dim3((M_ROWS / 256) * (HID / 256)), 512, 0, stream>>>
        (attnb, WoT, outp, M_ROWS, HID, O_N);
}